// Round 1
// baseline (1977.490 us; speedup 1.0000x reference)
//
#include <hip/hip_runtime.h>
#include <math.h>

#define NEG_SLOPE 0.2f

// ---------------- GEMM: C[M,N] = A[M,K] @ B[K,N] (+bias), row-major ----------------
// A tight (lda=K), B has ldb, C has ldc. K % 16 == 0, N % 64 == 0 required.
__global__ __launch_bounds__(256) void gemm_tiled(
    const float* __restrict__ A, const float* __restrict__ B, int ldb,
    const float* __restrict__ bias, float* __restrict__ C, int ldc,
    int M, int N, int K)
{
  const int bm = blockIdx.y * 64;
  const int bn = blockIdx.x * 64;
  const int tid = threadIdx.x;
  const int tx = tid & 15, ty = tid >> 4;
  __shared__ float As[16][65];   // +1 pad: kills 4-way bank conflict on writes
  __shared__ float Bs[16][64];
  float acc[4][4] = {{0.f}};
  const int arow = tid >> 2;            // 0..63
  const int acol = (tid & 3) << 2;      // 0,4,8,12
  const int brow = tid >> 4;            // 0..15
  const int bcol = (tid & 15) << 2;     // 0..60
  const bool a_ok = (bm + arow) < M;
  const float* Aptr = A + (size_t)(bm + arow) * K + acol;
  const float* Bptr = B + (size_t)brow * ldb + bn + bcol;

  for (int k0 = 0; k0 < K; k0 += 16) {
    float4 av = make_float4(0.f, 0.f, 0.f, 0.f);
    if (a_ok) av = *(const float4*)(Aptr + k0);
    float4 bv = *(const float4*)(Bptr + (size_t)k0 * ldb);
    As[acol + 0][arow] = av.x; As[acol + 1][arow] = av.y;
    As[acol + 2][arow] = av.z; As[acol + 3][arow] = av.w;
    *(float4*)&Bs[brow][bcol] = bv;
    __syncthreads();
#pragma unroll
    for (int k = 0; k < 16; ++k) {
      float a0[4], b0[4];
#pragma unroll
      for (int i = 0; i < 4; ++i) a0[i] = As[k][ty * 4 + i];
#pragma unroll
      for (int j = 0; j < 4; ++j) b0[j] = Bs[k][tx * 4 + j];
#pragma unroll
      for (int i = 0; i < 4; ++i)
#pragma unroll
        for (int j = 0; j < 4; ++j) acc[i][j] = fmaf(a0[i], b0[j], acc[i][j]);
    }
    __syncthreads();
  }
#pragma unroll
  for (int i = 0; i < 4; ++i) {
    int r = bm + ty * 4 + i;
    if (r >= M) continue;
#pragma unroll
    for (int j = 0; j < 4; ++j) {
      int c = bn + tx * 4 + j;
      float v = acc[i][j];
      if (bias) v += bias[c];
      C[(size_t)r * ldc + c] = v;
    }
  }
}

// ---------------- CSR build ----------------
__global__ void count_deg(const int* __restrict__ ei, int E, int* __restrict__ deg)
{
  int e = blockIdx.x * 256 + threadIdx.x;
  if (e < E) atomicAdd(&deg[ei[E + e]], 1);
}

__global__ void fill_csr(const int* __restrict__ ei, int E, int* __restrict__ cursor,
                         const int* __restrict__ rowptr, int* __restrict__ csr_src)
{
  int e = blockIdx.x * 256 + threadIdx.x;
  if (e < E) {
    int d = ei[E + e];
    int pos = atomicAdd(&cursor[d], 1);
    csr_src[rowptr[d] + pos] = ei[e];
  }
}

__global__ void count_graph(const int* __restrict__ batch, int N, int* __restrict__ gcnt)
{
  int i = blockIdx.x * 256 + threadIdx.x;
  if (i < N) atomicAdd(&gcnt[batch[i]], 1);
}

// exclusive scan, single block (1024 threads), n up to ~128k
__global__ void scan_excl(const int* __restrict__ vals, int* __restrict__ rowptr, int n)
{
  const int t = threadIdx.x;
  const int nt = blockDim.x;
  const int per = (n + nt - 1) / nt;
  const int beg = t * per;
  const int end = min(beg + per, n);
  int s = 0;
  for (int i = beg; i < end; ++i) s += vals[i];
  __shared__ int tmp[1024];
  tmp[t] = s;
  __syncthreads();
  for (int off = 1; off < nt; off <<= 1) {
    int add = (t >= off) ? tmp[t - off] : 0;
    __syncthreads();
    tmp[t] += add;
    __syncthreads();
  }
  int run = tmp[t] - s;   // exclusive prefix of this chunk
  for (int i = beg; i < end; ++i) { rowptr[i] = run; run += vals[i]; }
  if (t == nt - 1) rowptr[n] = tmp[nt - 1];
}

// ---------------- attention coefficients: e_src/e_dst per (node, head) ----------------
// block = nheads*C threads (one per channel); wave(64)-reduce then combine
__global__ void compute_e_kernel(const float* __restrict__ h,
                                 const float* __restrict__ a_src,
                                 const float* __restrict__ a_dst,
                                 float* __restrict__ es, float* __restrict__ ed,
                                 int nheads, int C)
{
  const int HC = nheads * C;
  const int node = blockIdx.x;
  const int t = threadIdx.x;
  float hv = h[(size_t)node * HC + t];
  float ps = hv * a_src[t];
  float pd = hv * a_dst[t];
  for (int off = 32; off; off >>= 1) {
    ps += __shfl_down(ps, off, 64);
    pd += __shfl_down(pd, off, 64);
  }
  __shared__ float ss[8], sd[8];
  const int wave = t >> 6;
  if ((t & 63) == 0) { ss[wave] = ps; sd[wave] = pd; }
  __syncthreads();
  const int wph = C >> 6;  // waves per head (1 for C=64, 2 for C=128)
  if (t < nheads) {
    float s = 0.f, d = 0.f;
    for (int w = 0; w < wph; ++w) { s += ss[t * wph + w]; d += sd[t * wph + w]; }
    es[(size_t)node * nheads + t] = s;
    ed[(size_t)node * nheads + t] = d;
  }
}

// ---------------- softmax-weighted gather aggregation + bias + ELU ----------------
// one block per dst node, nheads*C threads (one per output channel)
__global__ void aggregate_kernel(const float* __restrict__ h,
                                 const float* __restrict__ es,
                                 const float* __restrict__ ed,
                                 const int* __restrict__ rowptr,
                                 const int* __restrict__ csr_src,
                                 const float* __restrict__ bias,
                                 float* __restrict__ out,
                                 int nheads, int C)
{
  const int HC = nheads * C;
  const int dst = blockIdx.x;
  const int t = threadIdx.x;
  const int head = t / C;
  const int beg = rowptr[dst], end = rowptr[dst + 1];
  __shared__ float denom_s[8];
  if (t < nheads) {
    const float edh = ed[(size_t)dst * nheads + t];
    float dsum = 0.f;
    for (int e = beg; e < end; ++e) {
      int s = csr_src[e];
      float l = es[(size_t)s * nheads + t] + edh;
      l = l >= 0.f ? l : NEG_SLOPE * l;
      dsum += expf(l);
    }
    float ls = es[(size_t)dst * nheads + t] + edh;   // self-loop
    ls = ls >= 0.f ? ls : NEG_SLOPE * ls;
    dsum += expf(ls);
    denom_s[t] = dsum;
  }
  __syncthreads();
  const float my_ed = ed[(size_t)dst * nheads + head];
  const float inv_den = 1.0f / denom_s[head];
  float acc = 0.f;
  for (int e = beg; e < end; ++e) {
    int s = csr_src[e];
    float l = es[(size_t)s * nheads + head] + my_ed;
    l = l >= 0.f ? l : NEG_SLOPE * l;
    acc = fmaf(expf(l) * inv_den, h[(size_t)s * HC + t], acc);
  }
  {
    float l = es[(size_t)dst * nheads + head] + my_ed;  // self-loop
    l = l >= 0.f ? l : NEG_SLOPE * l;
    acc = fmaf(expf(l) * inv_den, h[(size_t)dst * HC + t], acc);
  }
  float v = acc + bias[t];
  out[(size_t)dst * HC + t] = v > 0.f ? v : (expf(v) - 1.0f);  // ELU fused
}

// ---------------- per-graph mean pool (sorted batch -> rowptr_g) ----------------
__global__ void pool_mean_kernel(const float* __restrict__ h, int in_stride,
                                 const int* __restrict__ grp,
                                 float* __restrict__ pooled, int out_stride)
{
  const int g = blockIdx.x;
  const int t = threadIdx.x;
  const int beg = grp[g], end = grp[g + 1];
  float acc = 0.f;
  for (int i = beg; i < end; ++i) acc += h[(size_t)i * in_stride + t];
  int cnt = end - beg; if (cnt < 1) cnt = 1;
  pooled[(size_t)g * out_stride + t] = acc / (float)cnt;
}

// ---------------- fused fc1(relu) + fc2 head, one block (64 threads) per graph ----------------
__global__ void mlp_head(const float* __restrict__ pooled, const float* __restrict__ fph,
                         const float* __restrict__ Wfc1, const float* __restrict__ bfc1,
                         const float* __restrict__ Wfc2, const float* __restrict__ bfc2,
                         float* __restrict__ out)
{
  const int g = blockIdx.x;
  const int j = threadIdx.x;  // 64 hidden units = one wave
  float acc = bfc1[j];
  const float* pz = pooled + (size_t)g * 512;
  for (int k = 0; k < 512; ++k) acc = fmaf(pz[k], Wfc1[k * 64 + j], acc);
  const float* pf = fph + (size_t)g * 64;
  for (int k = 0; k < 64; ++k) acc = fmaf(pf[k], Wfc1[(512 + k) * 64 + j], acc);
  acc = acc > 0.f ? acc : 0.f;                 // relu
  float term = acc * Wfc2[j];
  for (int off = 32; off; off >>= 1) term += __shfl_down(term, off, 64);
  if (j == 0) out[g] = term + bfc2[0];
}

// ---------------- launcher ----------------
extern "C" void kernel_launch(void* const* d_in, const int* in_sizes, int n_in,
                              void* d_out, int out_size, void* d_ws, size_t ws_size,
                              hipStream_t stream)
{
  const float* x      = (const float*)d_in[0];
  const int*   ei     = (const int*)d_in[1];
  const int*   batch  = (const int*)d_in[2];
  const float* fp     = (const float*)d_in[3];
  const float* W1     = (const float*)d_in[4];
  const float* a_src1 = (const float*)d_in[5];
  const float* a_dst1 = (const float*)d_in[6];
  const float* b1     = (const float*)d_in[7];
  const float* W2     = (const float*)d_in[8];
  const float* a_src2 = (const float*)d_in[9];
  const float* a_dst2 = (const float*)d_in[10];
  const float* b2     = (const float*)d_in[11];
  const float* Wfp    = (const float*)d_in[12];
  const float* bfp    = (const float*)d_in[13];
  const float* Wfc1   = (const float*)d_in[14];
  const float* bfc1   = (const float*)d_in[15];
  const float* Wfc2   = (const float*)d_in[16];
  const float* bfc2   = (const float*)d_in[17];
  float* out = (float*)d_out;

  const int N = in_sizes[0] / 128;     // 100000 nodes
  const int E = in_sizes[1] / 2;       // 400000 edges
  const int G = in_sizes[3] / 2048;    // 2048 graphs
  const int FIN = 128, H = 4, C1 = 64, C2 = 128;
  const int HC1 = H * C1;              // 256
  const int HC2 = H * C2;              // 512

  // workspace layout (floats). conv2 per-head buffers reuse the h1 region.
  float* fbase  = (float*)d_ws;
  float* h1     = fbase;                         // [N,256]
  float* h2h    = fbase;                         // [N,128] (reuse, h1 dead by then)
  float* agg2h  = fbase + (size_t)N * C2;        // [N,128]
  float* agg1   = fbase + (size_t)N * HC1;       // [N,256]
  size_t off    = (size_t)N * HC1 * 2;           // N*512
  float* es1    = fbase + off; off += (size_t)N * H;
  float* ed1    = fbase + off; off += (size_t)N * H;
  float* es2    = fbase + off; off += (size_t)N;
  float* ed2    = fbase + off; off += (size_t)N;
  float* pooled = fbase + off; off += (size_t)G * HC2;
  float* fph    = fbase + off; off += (size_t)G * 64;
  int* ibase    = (int*)(fbase + off);
  int* deg      = ibase;                         // [N]   } zeroed
  int* cursor   = ibase + N;                     // [N]   } every
  int* gcnt     = ibase + 2 * N;                 // [G]   } call
  int* rowptr_n = ibase + 2 * N + G;             // [N+1]
  int* rowptr_g = rowptr_n + (N + 1);            // [G+1]
  int* csr_src  = rowptr_g + (G + 1);            // [E]

  hipMemsetAsync(ibase, 0, sizeof(int) * (2 * (size_t)N + G), stream);

  // CSR by dst + graph segment ptrs
  count_deg<<<(E + 255) / 256, 256, 0, stream>>>(ei, E, deg);
  scan_excl<<<1, 1024, 0, stream>>>(deg, rowptr_n, N);
  fill_csr<<<(E + 255) / 256, 256, 0, stream>>>(ei, E, cursor, rowptr_n, csr_src);
  count_graph<<<(N + 255) / 256, 256, 0, stream>>>(batch, N, gcnt);
  scan_excl<<<1, 1024, 0, stream>>>(gcnt, rowptr_g, G);

  // conv1
  dim3 g1(HC1 / 64, (N + 63) / 64);
  gemm_tiled<<<g1, 256, 0, stream>>>(x, W1, HC1, nullptr, h1, HC1, N, HC1, FIN);
  compute_e_kernel<<<N, HC1, 0, stream>>>(h1, a_src1, a_dst1, es1, ed1, H, C1);
  aggregate_kernel<<<N, HC1, 0, stream>>>(h1, es1, ed1, rowptr_n, csr_src, b1, agg1, H, C1);

  // conv2, head-by-head (caps workspace at ~217 MB)
  for (int hd = 0; hd < H; ++hd) {
    dim3 g2(C2 / 64, (N + 63) / 64);
    gemm_tiled<<<g2, 256, 0, stream>>>(agg1, W2 + hd * C2, HC2, nullptr, h2h, C2, N, C2, HC1);
    compute_e_kernel<<<N, C2, 0, stream>>>(h2h, a_src2 + (size_t)hd * C2, a_dst2 + (size_t)hd * C2,
                                           es2, ed2, 1, C2);
    aggregate_kernel<<<N, C2, 0, stream>>>(h2h, es2, ed2, rowptr_n, csr_src,
                                           b2 + (size_t)hd * C2, agg2h, 1, C2);
    pool_mean_kernel<<<G, C2, 0, stream>>>(agg2h, C2, rowptr_g, pooled + (size_t)hd * C2, HC2);
  }

  // fingerprint MLP + fused head
  dim3 g3(1, (G + 63) / 64);
  gemm_tiled<<<g3, 256, 0, stream>>>(fp, Wfp, 64, bfp, fph, 64, G, 64, 2048);
  mlp_head<<<G, 64, 0, stream>>>(pooled, fph, Wfc1, bfc1, Wfc2, bfc2, out);
}

// Round 2
// 1609.942 us; speedup vs baseline: 1.2283x; 1.2283x over previous
//
#include <hip/hip_runtime.h>
#include <math.h>

#define NEG_SLOPE 0.2f

// ---------------- GEMM: C[M,N] = A[M,K] @ B[K,N] (+bias), row-major ----------------
__global__ __launch_bounds__(256) void gemm_tiled(
    const float* __restrict__ A, const float* __restrict__ B, int ldb,
    const float* __restrict__ bias, float* __restrict__ C, int ldc,
    int M, int N, int K)
{
  const int bm = blockIdx.y * 64;
  const int bn = blockIdx.x * 64;
  const int tid = threadIdx.x;
  const int tx = tid & 15, ty = tid >> 4;
  __shared__ float As[16][65];
  __shared__ float Bs[16][64];
  float acc[4][4] = {{0.f}};
  const int arow = tid >> 2;
  const int acol = (tid & 3) << 2;
  const int brow = tid >> 4;
  const int bcol = (tid & 15) << 2;
  const bool a_ok = (bm + arow) < M;
  const float* Aptr = A + (size_t)(bm + arow) * K + acol;
  const float* Bptr = B + (size_t)brow * ldb + bn + bcol;

  for (int k0 = 0; k0 < K; k0 += 16) {
    float4 av = make_float4(0.f, 0.f, 0.f, 0.f);
    if (a_ok) av = *(const float4*)(Aptr + k0);
    float4 bv = *(const float4*)(Bptr + (size_t)k0 * ldb);
    As[acol + 0][arow] = av.x; As[acol + 1][arow] = av.y;
    As[acol + 2][arow] = av.z; As[acol + 3][arow] = av.w;
    *(float4*)&Bs[brow][bcol] = bv;
    __syncthreads();
#pragma unroll
    for (int k = 0; k < 16; ++k) {
      float a0[4], b0[4];
#pragma unroll
      for (int i = 0; i < 4; ++i) a0[i] = As[k][ty * 4 + i];
#pragma unroll
      for (int j = 0; j < 4; ++j) b0[j] = Bs[k][tx * 4 + j];
#pragma unroll
      for (int i = 0; i < 4; ++i)
#pragma unroll
        for (int j = 0; j < 4; ++j) acc[i][j] = fmaf(a0[i], b0[j], acc[i][j]);
    }
    __syncthreads();
  }
#pragma unroll
  for (int i = 0; i < 4; ++i) {
    int r = bm + ty * 4 + i;
    if (r >= M) continue;
#pragma unroll
    for (int j = 0; j < 4; ++j) {
      int c = bn + tx * 4 + j;
      float v = acc[i][j];
      if (bias) v += bias[c];
      C[(size_t)r * ldc + c] = v;
    }
  }
}

// ---------------- CSR build ----------------
__global__ void count_deg(const int* __restrict__ ei, int E, int* __restrict__ deg)
{
  int e = blockIdx.x * 256 + threadIdx.x;
  if (e < E) atomicAdd(&deg[ei[E + e]], 1);
}

__global__ void fill_csr(const int* __restrict__ ei, int E, int* __restrict__ cursor,
                         const int* __restrict__ rowptr, int* __restrict__ csr_src)
{
  int e = blockIdx.x * 256 + threadIdx.x;
  if (e < E) {
    int d = ei[E + e];
    int pos = atomicAdd(&cursor[d], 1);
    csr_src[rowptr[d] + pos] = ei[e];
  }
}

__global__ void count_graph(const int* __restrict__ batch, int N, int* __restrict__ gcnt)
{
  int i = blockIdx.x * 256 + threadIdx.x;
  if (i < N) atomicAdd(&gcnt[batch[i]], 1);
}

// exclusive scan, single block
__global__ void scan_excl(const int* __restrict__ vals, int* __restrict__ rowptr, int n)
{
  const int t = threadIdx.x;
  const int nt = blockDim.x;
  const int per = (n + nt - 1) / nt;
  const int beg = t * per;
  const int end = min(beg + per, n);
  int s = 0;
  for (int i = beg; i < end; ++i) s += vals[i];
  __shared__ int tmp[1024];
  tmp[t] = s;
  __syncthreads();
  for (int off = 1; off < nt; off <<= 1) {
    int add = (t >= off) ? tmp[t - off] : 0;
    __syncthreads();
    tmp[t] += add;
    __syncthreads();
  }
  int run = tmp[t] - s;
  for (int i = beg; i < end; ++i) { rowptr[i] = run; run += vals[i]; }
  if (t == nt - 1) rowptr[n] = tmp[nt - 1];
}

// ---------------- attention coefficients: e_src/e_dst per (node, head) ----------------
__global__ void compute_e_kernel(const float* __restrict__ h,
                                 const float* __restrict__ a_src,
                                 const float* __restrict__ a_dst,
                                 float* __restrict__ es, float* __restrict__ ed,
                                 int nheads, int C)
{
  const int HC = nheads * C;
  const int node = blockIdx.x;
  const int t = threadIdx.x;
  float hv = h[(size_t)node * HC + t];
  float ps = hv * a_src[t];
  float pd = hv * a_dst[t];
  for (int off = 32; off; off >>= 1) {
    ps += __shfl_down(ps, off, 64);
    pd += __shfl_down(pd, off, 64);
  }
  __shared__ float ss[8], sd[8];
  const int wave = t >> 6;
  if ((t & 63) == 0) { ss[wave] = ps; sd[wave] = pd; }
  __syncthreads();
  const int wph = C >> 6;
  if (t < nheads) {
    float s = 0.f, d = 0.f;
    for (int w = 0; w < wph; ++w) { s += ss[t * wph + w]; d += sd[t * wph + w]; }
    es[(size_t)node * nheads + t] = s;
    ed[(size_t)node * nheads + t] = d;
  }
}

// ---------------- normalized attention weights per edge-slot + self-loop ----------------
// one thread per (dst, head); CSR walk (avg degree ~5)
__global__ void alpha_kernel(const float* __restrict__ es, const float* __restrict__ ed,
                             const int* __restrict__ rowptr, const int* __restrict__ csr_src,
                             float* __restrict__ w_csr, float* __restrict__ wself,
                             int N, int nh)
{
  int idx = blockIdx.x * 256 + threadIdx.x;
  if (idx >= N * nh) return;
  const int dst = idx / nh;
  const int h = idx - dst * nh;
  const float edh = ed[(size_t)dst * nh + h];
  const int beg = rowptr[dst], end = rowptr[dst + 1];
  float sum = 0.f;
  for (int e = beg; e < end; ++e) {
    int s = csr_src[e];
    float l = es[(size_t)s * nh + h] + edh;
    l = l >= 0.f ? l : NEG_SLOPE * l;
    float w = expf(l);
    w_csr[(size_t)e * nh + h] = w;
    sum += w;
  }
  float ls = es[(size_t)dst * nh + h] + edh;  // self-loop
  ls = ls >= 0.f ? ls : NEG_SLOPE * ls;
  float wsl = expf(ls);
  sum += wsl;
  const float inv = 1.0f / sum;
  for (int e = beg; e < end; ++e) w_csr[(size_t)e * nh + h] *= inv;
  wself[(size_t)dst * nh + h] = wsl * inv;
}

// ---------------- weighted gather aggregation + bias + ELU (float4 per lane) ----------------
// CH4 = HC/4 lanes per dst; block 256 threads = (256/CH4) dsts
__global__ __launch_bounds__(256) void aggregate_v2(
    const float* __restrict__ h,
    const float* __restrict__ w_csr, const float* __restrict__ wself,
    const int* __restrict__ rowptr, const int* __restrict__ csr_src,
    const float* __restrict__ bias, float* __restrict__ out,
    int N, int nh, int C)
{
  const int HC = nh * C;
  const int CH4 = HC >> 2;             // lanes per dst (64 or 32)
  const int dpb = 256 / CH4;           // dsts per block (4 or 8)
  const int grp = threadIdx.x / CH4;
  const int lane = threadIdx.x - grp * CH4;
  const int dst = blockIdx.x * dpb + grp;
  if (dst >= N) return;
  const int ch = lane << 2;            // channel offset (float4)
  const int head = ch / C;
  const int beg = rowptr[dst], end = rowptr[dst + 1];
  float4 acc = make_float4(0.f, 0.f, 0.f, 0.f);
  for (int e = beg; e < end; ++e) {
    int s = csr_src[e];
    float a = w_csr[(size_t)e * nh + head];
    float4 hv = *(const float4*)(h + (size_t)s * HC + ch);
    acc.x = fmaf(a, hv.x, acc.x);
    acc.y = fmaf(a, hv.y, acc.y);
    acc.z = fmaf(a, hv.z, acc.z);
    acc.w = fmaf(a, hv.w, acc.w);
  }
  {
    float a = wself[(size_t)dst * nh + head];
    float4 hv = *(const float4*)(h + (size_t)dst * HC + ch);
    acc.x = fmaf(a, hv.x, acc.x);
    acc.y = fmaf(a, hv.y, acc.y);
    acc.z = fmaf(a, hv.z, acc.z);
    acc.w = fmaf(a, hv.w, acc.w);
  }
  float4 bv = *(const float4*)(bias + ch);
  float4 v;
  v.x = acc.x + bv.x; v.y = acc.y + bv.y;
  v.z = acc.z + bv.z; v.w = acc.w + bv.w;
  v.x = v.x > 0.f ? v.x : (expf(v.x) - 1.0f);
  v.y = v.y > 0.f ? v.y : (expf(v.y) - 1.0f);
  v.z = v.z > 0.f ? v.z : (expf(v.z) - 1.0f);
  v.w = v.w > 0.f ? v.w : (expf(v.w) - 1.0f);
  *(float4*)(out + (size_t)dst * HC + ch) = v;
}

// ---------------- per-graph mean pool ----------------
__global__ void pool_mean_kernel(const float* __restrict__ h, int in_stride,
                                 const int* __restrict__ grp,
                                 float* __restrict__ pooled, int out_stride)
{
  const int g = blockIdx.x;
  const int t = threadIdx.x;
  const int beg = grp[g], end = grp[g + 1];
  float acc = 0.f;
  for (int i = beg; i < end; ++i) acc += h[(size_t)i * in_stride + t];
  int cnt = end - beg; if (cnt < 1) cnt = 1;
  pooled[(size_t)g * out_stride + t] = acc / (float)cnt;
}

// ---------------- fused fc1(relu) + fc2 head ----------------
__global__ void mlp_head(const float* __restrict__ pooled, const float* __restrict__ fph,
                         const float* __restrict__ Wfc1, const float* __restrict__ bfc1,
                         const float* __restrict__ Wfc2, const float* __restrict__ bfc2,
                         float* __restrict__ out)
{
  const int g = blockIdx.x;
  const int j = threadIdx.x;
  float acc = bfc1[j];
  const float* pz = pooled + (size_t)g * 512;
  for (int k = 0; k < 512; ++k) acc = fmaf(pz[k], Wfc1[k * 64 + j], acc);
  const float* pf = fph + (size_t)g * 64;
  for (int k = 0; k < 64; ++k) acc = fmaf(pf[k], Wfc1[(512 + k) * 64 + j], acc);
  acc = acc > 0.f ? acc : 0.f;
  float term = acc * Wfc2[j];
  for (int off = 32; off; off >>= 1) term += __shfl_down(term, off, 64);
  if (j == 0) out[g] = term + bfc2[0];
}

// ---------------- launcher ----------------
extern "C" void kernel_launch(void* const* d_in, const int* in_sizes, int n_in,
                              void* d_out, int out_size, void* d_ws, size_t ws_size,
                              hipStream_t stream)
{
  const float* x      = (const float*)d_in[0];
  const int*   ei     = (const int*)d_in[1];
  const int*   batch  = (const int*)d_in[2];
  const float* fp     = (const float*)d_in[3];
  const float* W1     = (const float*)d_in[4];
  const float* a_src1 = (const float*)d_in[5];
  const float* a_dst1 = (const float*)d_in[6];
  const float* b1     = (const float*)d_in[7];
  const float* W2     = (const float*)d_in[8];
  const float* a_src2 = (const float*)d_in[9];
  const float* a_dst2 = (const float*)d_in[10];
  const float* b2     = (const float*)d_in[11];
  const float* Wfp    = (const float*)d_in[12];
  const float* bfp    = (const float*)d_in[13];
  const float* Wfc1   = (const float*)d_in[14];
  const float* bfc1   = (const float*)d_in[15];
  const float* Wfc2   = (const float*)d_in[16];
  const float* bfc2   = (const float*)d_in[17];
  float* out = (float*)d_out;

  const int N = in_sizes[0] / 128;
  const int E = in_sizes[1] / 2;
  const int G = in_sizes[3] / 2048;
  const int FIN = 128, H = 4, C1 = 64, C2 = 128;
  const int HC1 = H * C1;   // 256
  const int HC2 = H * C2;   // 512

  // workspace layout (floats)
  float* fbase  = (float*)d_ws;
  float* h1     = fbase;                         // [N,256]
  float* h2h    = fbase;                         // [N,128] (reuse after conv1)
  float* agg2h  = fbase + (size_t)N * C2;        // [N,128] (inside dead h1 region)
  float* agg1   = fbase + (size_t)N * HC1;       // [N,256]
  size_t off    = (size_t)N * HC1 * 2;
  float* es1    = fbase + off; off += (size_t)N * H;
  float* ed1    = fbase + off; off += (size_t)N * H;
  float* es2    = fbase + off; off += (size_t)N;
  float* ed2    = fbase + off; off += (size_t)N;
  float* pooled = fbase + off; off += (size_t)G * HC2;
  float* fph    = fbase + off; off += (size_t)G * 64;
  float* w1     = fbase + off; off += (size_t)E * H;   // alpha per edge-slot, conv1
  float* wself1 = fbase + off; off += (size_t)N * H;
  float* w2     = fbase + off; off += (size_t)E;       // alpha per edge-slot, conv2 head
  float* wself2 = fbase + off; off += (size_t)N;
  int* ibase    = (int*)(fbase + off);
  int* deg      = ibase;
  int* cursor   = ibase + N;
  int* gcnt     = ibase + 2 * N;
  int* rowptr_n = ibase + 2 * N + G;
  int* rowptr_g = rowptr_n + (N + 1);
  int* csr_src  = rowptr_g + (G + 1);

  hipMemsetAsync(ibase, 0, sizeof(int) * (2 * (size_t)N + G), stream);

  // CSR by dst + graph segment ptrs
  count_deg<<<(E + 255) / 256, 256, 0, stream>>>(ei, E, deg);
  scan_excl<<<1, 1024, 0, stream>>>(deg, rowptr_n, N);
  fill_csr<<<(E + 255) / 256, 256, 0, stream>>>(ei, E, cursor, rowptr_n, csr_src);
  count_graph<<<(N + 255) / 256, 256, 0, stream>>>(batch, N, gcnt);
  scan_excl<<<1, 1024, 0, stream>>>(gcnt, rowptr_g, G);

  // conv1
  dim3 g1(HC1 / 64, (N + 63) / 64);
  gemm_tiled<<<g1, 256, 0, stream>>>(x, W1, HC1, nullptr, h1, HC1, N, HC1, FIN);
  compute_e_kernel<<<N, HC1, 0, stream>>>(h1, a_src1, a_dst1, es1, ed1, H, C1);
  alpha_kernel<<<(N * H + 255) / 256, 256, 0, stream>>>(es1, ed1, rowptr_n, csr_src,
                                                        w1, wself1, N, H);
  aggregate_v2<<<(N + 3) / 4, 256, 0, stream>>>(h1, w1, wself1, rowptr_n, csr_src,
                                                b1, agg1, N, H, C1);

  // conv2, head-by-head
  for (int hd = 0; hd < H; ++hd) {
    dim3 g2(C2 / 64, (N + 63) / 64);
    gemm_tiled<<<g2, 256, 0, stream>>>(agg1, W2 + hd * C2, HC2, nullptr, h2h, C2, N, C2, HC1);
    compute_e_kernel<<<N, C2, 0, stream>>>(h2h, a_src2 + (size_t)hd * C2, a_dst2 + (size_t)hd * C2,
                                           es2, ed2, 1, C2);
    alpha_kernel<<<(N + 255) / 256, 256, 0, stream>>>(es2, ed2, rowptr_n, csr_src,
                                                      w2, wself2, N, 1);
    aggregate_v2<<<(N + 7) / 8, 256, 0, stream>>>(h2h, w2, wself2, rowptr_n, csr_src,
                                                  b2 + (size_t)hd * C2, agg2h, N, 1, C2);
    pool_mean_kernel<<<G, C2, 0, stream>>>(agg2h, C2, rowptr_g, pooled + (size_t)hd * C2, HC2);
  }

  // fingerprint MLP + fused head
  dim3 g3(1, (G + 63) / 64);
  gemm_tiled<<<g3, 256, 0, stream>>>(fp, Wfp, 64, bfp, fph, 64, G, 64, 2048);
  mlp_head<<<G, 64, 0, stream>>>(pooled, fph, Wfc1, bfc1, Wfc2, bfc2, out);
}

// Round 3
// 1011.626 us; speedup vs baseline: 1.9548x; 1.5914x over previous
//
#include <hip/hip_runtime.h>
#include <math.h>

#define NEG_SLOPE 0.2f

typedef __attribute__((ext_vector_type(8))) short bf16x8;   // 8 bf16 (4 VGPRs)
typedef __attribute__((ext_vector_type(4))) float f32x4;    // MFMA acc

__device__ __forceinline__ float b2f(short s) {
  return __uint_as_float(((unsigned int)(unsigned short)s) << 16);
}
__device__ __forceinline__ unsigned short f2b_rne(float f) {
  unsigned int u = __float_as_uint(f);
  u = (u + 0x7FFF + ((u >> 16) & 1)) >> 16;
  return (unsigned short)u;
}

// ---------------- fp32 -> bf16 elementwise ----------------
__global__ void cvt_f2b(const float* __restrict__ in, unsigned short* __restrict__ out, size_t n)
{
  size_t i = (size_t)blockIdx.x * 256 + threadIdx.x;
  size_t stride = (size_t)gridDim.x * 256;
  for (; i < n; i += stride) out[i] = f2b_rne(in[i]);
}

// ---------------- W [K,N] f32 -> WT [N,K] bf16 ----------------
__global__ void transpose_f2b(const float* __restrict__ W, unsigned short* __restrict__ WT,
                              int K, int N)
{
  int idx = blockIdx.x * 256 + threadIdx.x;
  if (idx < K * N) {
    int k = idx / N, n = idx - k * N;
    WT[(size_t)n * K + k] = f2b_rne(W[idx]);
  }
}

// ---------------- MFMA GEMM: C[M,N] = A[M,K] @ B[K,N] ----------------
// A bf16 [M,K] row-major, BT bf16 [N,K] row-major (pre-transposed B).
// BM=BN=128, BK=32, 256 threads = 4 waves (2x2 of 64x64 each).
// N must be a multiple of 128; K a multiple of 32.
template<int WRITE_BF16>
__global__ __launch_bounds__(256) void gemm_mfma(
    const unsigned short* __restrict__ A, const unsigned short* __restrict__ BT,
    void* __restrict__ Cout, int M, int N, int K)
{
  const int LDT = 40;   // padded LDS row stride (bf16): 80 B, 16B-aligned, spreads banks
  __shared__ unsigned short As[128 * 40];
  __shared__ unsigned short Bs[128 * 40];
  const int tid  = threadIdx.x;
  const int wave = tid >> 6;
  const int lane = tid & 63;
  const int ln   = lane & 15;
  const int quad = lane >> 4;
  const int wr0  = (wave >> 1) * 64;
  const int wc0  = (wave & 1) * 64;
  const int bm   = blockIdx.y * 128;
  const int bn   = blockIdx.x * 128;
  const int srow  = tid >> 2;         // 0..63
  const int skoff = (tid & 3) * 8;    // 0,8,16,24

  f32x4 acc[4][4];
  const f32x4 z4 = {0.f, 0.f, 0.f, 0.f};
#pragma unroll
  for (int i = 0; i < 4; ++i)
#pragma unroll
    for (int j = 0; j < 4; ++j) acc[i][j] = z4;

  for (int k0 = 0; k0 < K; k0 += 32) {
#pragma unroll
    for (int p = 0; p < 2; ++p) {
      int r = srow + p * 64;
      bf16x8 va = {0, 0, 0, 0, 0, 0, 0, 0};
      if (bm + r < M)
        va = *(const bf16x8*)(A + (size_t)(bm + r) * K + k0 + skoff);
      *(bf16x8*)(&As[r * LDT + skoff]) = va;
      bf16x8 vb = *(const bf16x8*)(BT + (size_t)(bn + r) * K + k0 + skoff);
      *(bf16x8*)(&Bs[r * LDT + skoff]) = vb;
    }
    __syncthreads();
    bf16x8 af[4], bfv[4];
#pragma unroll
    for (int i = 0; i < 4; ++i)
      af[i] = *(const bf16x8*)(&As[(wr0 + i * 16 + ln) * LDT + quad * 8]);
#pragma unroll
    for (int j = 0; j < 4; ++j)
      bfv[j] = *(const bf16x8*)(&Bs[(wc0 + j * 16 + ln) * LDT + quad * 8]);
#pragma unroll
    for (int i = 0; i < 4; ++i)
#pragma unroll
      for (int j = 0; j < 4; ++j)
        acc[i][j] = __builtin_amdgcn_mfma_f32_16x16x32_bf16(af[i], bfv[j], acc[i][j], 0, 0, 0);
    __syncthreads();
  }
  // epilogue: C/D layout col=lane&15, row=quad*4+reg
#pragma unroll
  for (int i = 0; i < 4; ++i) {
#pragma unroll
    for (int r = 0; r < 4; ++r) {
      int row = bm + wr0 + i * 16 + quad * 4 + r;
      if (row >= M) continue;
#pragma unroll
      for (int j = 0; j < 4; ++j) {
        int col = bn + wc0 + j * 16 + ln;
        float v = acc[i][j][r];
        if (WRITE_BF16)
          ((unsigned short*)Cout)[(size_t)row * N + col] = f2b_rne(v);
        else
          ((float*)Cout)[(size_t)row * N + col] = v;
      }
    }
  }
}

// ---------------- fp32 GEMM (for small fingerprint GEMM) ----------------
__global__ __launch_bounds__(256) void gemm_tiled(
    const float* __restrict__ A, const float* __restrict__ B, int ldb,
    const float* __restrict__ bias, float* __restrict__ C, int ldc,
    int M, int N, int K)
{
  const int bm = blockIdx.y * 64;
  const int bn = blockIdx.x * 64;
  const int tid = threadIdx.x;
  const int tx = tid & 15, ty = tid >> 4;
  __shared__ float As[16][65];
  __shared__ float Bs[16][64];
  float acc[4][4] = {{0.f}};
  const int arow = tid >> 2;
  const int acol = (tid & 3) << 2;
  const int brow = tid >> 4;
  const int bcol = (tid & 15) << 2;
  const bool a_ok = (bm + arow) < M;
  const float* Aptr = A + (size_t)(bm + arow) * K + acol;
  const float* Bptr = B + (size_t)brow * ldb + bn + bcol;

  for (int k0 = 0; k0 < K; k0 += 16) {
    float4 av = make_float4(0.f, 0.f, 0.f, 0.f);
    if (a_ok) av = *(const float4*)(Aptr + k0);
    float4 bv = *(const float4*)(Bptr + (size_t)k0 * ldb);
    As[acol + 0][arow] = av.x; As[acol + 1][arow] = av.y;
    As[acol + 2][arow] = av.z; As[acol + 3][arow] = av.w;
    *(float4*)&Bs[brow][bcol] = bv;
    __syncthreads();
#pragma unroll
    for (int k = 0; k < 16; ++k) {
      float a0[4], b0[4];
#pragma unroll
      for (int i = 0; i < 4; ++i) a0[i] = As[k][ty * 4 + i];
#pragma unroll
      for (int j = 0; j < 4; ++j) b0[j] = Bs[k][tx * 4 + j];
#pragma unroll
      for (int i = 0; i < 4; ++i)
#pragma unroll
        for (int j = 0; j < 4; ++j) acc[i][j] = fmaf(a0[i], b0[j], acc[i][j]);
    }
    __syncthreads();
  }
#pragma unroll
  for (int i = 0; i < 4; ++i) {
    int r = bm + ty * 4 + i;
    if (r >= M) continue;
#pragma unroll
    for (int j = 0; j < 4; ++j) {
      int c = bn + tx * 4 + j;
      float v = acc[i][j];
      if (bias) v += bias[c];
      C[(size_t)r * ldc + c] = v;
    }
  }
}

// ---------------- CSR build ----------------
__global__ void count_deg(const int* __restrict__ ei, int E, int* __restrict__ deg)
{
  int e = blockIdx.x * 256 + threadIdx.x;
  if (e < E) atomicAdd(&deg[ei[E + e]], 1);
}

__global__ void fill_csr(const int* __restrict__ ei, int E, int* __restrict__ cursor,
                         const int* __restrict__ rowptr, int* __restrict__ csr_src)
{
  int e = blockIdx.x * 256 + threadIdx.x;
  if (e < E) {
    int d = ei[E + e];
    int pos = atomicAdd(&cursor[d], 1);
    csr_src[rowptr[d] + pos] = ei[e];
  }
}

__global__ void count_graph(const int* __restrict__ batch, int N, int* __restrict__ gcnt)
{
  int i = blockIdx.x * 256 + threadIdx.x;
  if (i < N) atomicAdd(&gcnt[batch[i]], 1);
}

// ---------------- 3-phase exclusive scan (chunk=1024, up to 128 chunks) ----------------
__global__ void scan_p1(const int* __restrict__ vals, int n, int* __restrict__ bsum)
{
  __shared__ int red[256];
  int base = blockIdx.x * 1024;
  int t = threadIdx.x;
  int s = 0;
#pragma unroll
  for (int i = 0; i < 4; ++i) {
    int idx = base + i * 256 + t;
    if (idx < n) s += vals[idx];
  }
  red[t] = s;
  __syncthreads();
  for (int off = 128; off; off >>= 1) {
    if (t < off) red[t] += red[t + off];
    __syncthreads();
  }
  if (t == 0) bsum[blockIdx.x] = red[0];
}

__global__ void scan_p2(const int* __restrict__ bsum, int* __restrict__ bpre,
                        int nb, int* __restrict__ rowptr, int n)
{
  __shared__ int tmp[128];
  int t = threadIdx.x;
  int v = (t < nb) ? bsum[t] : 0;
  tmp[t] = v;
  __syncthreads();
  for (int off = 1; off < 128; off <<= 1) {
    int add = (t >= off) ? tmp[t - off] : 0;
    __syncthreads();
    tmp[t] += add;
    __syncthreads();
  }
  if (t < nb) bpre[t] = tmp[t] - v;
  if (t == 127) rowptr[n] = tmp[127];
}

__global__ void scan_p3(const int* __restrict__ vals, const int* __restrict__ bpre,
                        int n, int* __restrict__ rowptr)
{
  __shared__ int tmp[256];
  int t = threadIdx.x;
  int base = blockIdx.x * 1024 + t * 4;
  int v[4]; int s = 0;
#pragma unroll
  for (int i = 0; i < 4; ++i) {
    int idx = base + i;
    v[i] = (idx < n) ? vals[idx] : 0;
    s += v[i];
  }
  tmp[t] = s;
  __syncthreads();
  for (int off = 1; off < 256; off <<= 1) {
    int add = (t >= off) ? tmp[t - off] : 0;
    __syncthreads();
    tmp[t] += add;
    __syncthreads();
  }
  int run = bpre[blockIdx.x] + tmp[t] - s;
#pragma unroll
  for (int i = 0; i < 4; ++i) {
    int idx = base + i;
    if (idx < n) rowptr[idx] = run;
    run += v[i];
  }
}

// ---------------- e_src/e_dst per (node, head), bf16 h ----------------
__global__ void compute_e_b(const unsigned short* __restrict__ h,
                            const float* __restrict__ a_src,
                            const float* __restrict__ a_dst,
                            float* __restrict__ es, float* __restrict__ ed,
                            int nheads, int C)
{
  const int HC = nheads * C;
  const int node = blockIdx.x;
  const int t = threadIdx.x;
  float hv = b2f((short)h[(size_t)node * HC + t]);
  float ps = hv * a_src[t];
  float pd = hv * a_dst[t];
  for (int off = 32; off; off >>= 1) {
    ps += __shfl_down(ps, off, 64);
    pd += __shfl_down(pd, off, 64);
  }
  __shared__ float ss[8], sd[8];
  const int wave = t >> 6;
  if ((t & 63) == 0) { ss[wave] = ps; sd[wave] = pd; }
  __syncthreads();
  const int wph = C >> 6;
  if (t < nheads) {
    float s = 0.f, d = 0.f;
    for (int w = 0; w < wph; ++w) { s += ss[t * wph + w]; d += sd[t * wph + w]; }
    es[(size_t)node * nheads + t] = s;
    ed[(size_t)node * nheads + t] = d;
  }
}

// ---------------- normalized attention weights ----------------
__global__ void alpha_kernel(const float* __restrict__ es, const float* __restrict__ ed,
                             const int* __restrict__ rowptr, const int* __restrict__ csr_src,
                             float* __restrict__ w_csr, float* __restrict__ wself,
                             int N, int nh)
{
  int idx = blockIdx.x * 256 + threadIdx.x;
  if (idx >= N * nh) return;
  const int dst = idx / nh;
  const int h = idx - dst * nh;
  const float edh = ed[(size_t)dst * nh + h];
  const int beg = rowptr[dst], end = rowptr[dst + 1];
  float sum = 0.f;
  for (int e = beg; e < end; ++e) {
    int s = csr_src[e];
    float l = es[(size_t)s * nh + h] + edh;
    l = l >= 0.f ? l : NEG_SLOPE * l;
    float w = expf(l);
    w_csr[(size_t)e * nh + h] = w;
    sum += w;
  }
  float ls = es[(size_t)dst * nh + h] + edh;
  ls = ls >= 0.f ? ls : NEG_SLOPE * ls;
  float wsl = expf(ls);
  sum += wsl;
  const float inv = 1.0f / sum;
  for (int e = beg; e < end; ++e) w_csr[(size_t)e * nh + h] *= inv;
  wself[(size_t)dst * nh + h] = wsl * inv;
}

// ---------------- weighted gather aggregation + bias + ELU, bf16 h ----------------
// 8 channels per lane (16B gathers); OUT_BF16 selects output type
template<int OUT_BF16>
__global__ __launch_bounds__(256) void aggregate_b(
    const unsigned short* __restrict__ h,
    const float* __restrict__ w_csr, const float* __restrict__ wself,
    const int* __restrict__ rowptr, const int* __restrict__ csr_src,
    const float* __restrict__ bias, void* __restrict__ out,
    int N, int nh, int C)
{
  const int HC = nh * C;
  const int CH8 = HC >> 3;             // lanes per dst (32 or 16)
  const int dpb = 256 / CH8;           // dsts per block (8 or 16)
  const int grp = threadIdx.x / CH8;
  const int lane = threadIdx.x - grp * CH8;
  const int dst = blockIdx.x * dpb + grp;
  if (dst >= N) return;
  const int ch = lane << 3;
  const int head = ch / C;
  const int beg = rowptr[dst], end = rowptr[dst + 1];
  float acc[8] = {0.f, 0.f, 0.f, 0.f, 0.f, 0.f, 0.f, 0.f};
  for (int e = beg; e < end; ++e) {
    int s = csr_src[e];
    float a = w_csr[(size_t)e * nh + head];
    bf16x8 hv = *(const bf16x8*)(h + (size_t)s * HC + ch);
#pragma unroll
    for (int r = 0; r < 8; ++r) acc[r] = fmaf(a, b2f(hv[r]), acc[r]);
  }
  {
    float a = wself[(size_t)dst * nh + head];
    bf16x8 hv = *(const bf16x8*)(h + (size_t)dst * HC + ch);
#pragma unroll
    for (int r = 0; r < 8; ++r) acc[r] = fmaf(a, b2f(hv[r]), acc[r]);
  }
  if (OUT_BF16) {
    bf16x8 o;
#pragma unroll
    for (int r = 0; r < 8; ++r) {
      float v = acc[r] + bias[ch + r];
      v = v > 0.f ? v : (expf(v) - 1.0f);
      o[r] = (short)f2b_rne(v);
    }
    *(bf16x8*)((unsigned short*)out + (size_t)dst * HC + ch) = o;
  } else {
    float* op = (float*)out + (size_t)dst * HC + ch;
#pragma unroll
    for (int r = 0; r < 8; ++r) {
      float v = acc[r] + bias[ch + r];
      op[r] = v > 0.f ? v : (expf(v) - 1.0f);
    }
  }
}

// ---------------- per-graph mean pool ----------------
__global__ void pool_mean_kernel(const float* __restrict__ h, int in_stride,
                                 const int* __restrict__ grp,
                                 float* __restrict__ pooled, int out_stride)
{
  const int g = blockIdx.x;
  const int t = threadIdx.x;
  const int beg = grp[g], end = grp[g + 1];
  float acc = 0.f;
  for (int i = beg; i < end; ++i) acc += h[(size_t)i * in_stride + t];
  int cnt = end - beg; if (cnt < 1) cnt = 1;
  pooled[(size_t)g * out_stride + t] = acc / (float)cnt;
}

// ---------------- fused fc1(relu) + fc2 head ----------------
__global__ void mlp_head(const float* __restrict__ pooled, const float* __restrict__ fph,
                         const float* __restrict__ Wfc1, const float* __restrict__ bfc1,
                         const float* __restrict__ Wfc2, const float* __restrict__ bfc2,
                         float* __restrict__ out)
{
  const int g = blockIdx.x;
  const int j = threadIdx.x;
  float acc = bfc1[j];
  const float* pz = pooled + (size_t)g * 512;
  for (int k = 0; k < 512; ++k) acc = fmaf(pz[k], Wfc1[k * 64 + j], acc);
  const float* pf = fph + (size_t)g * 64;
  for (int k = 0; k < 64; ++k) acc = fmaf(pf[k], Wfc1[(512 + k) * 64 + j], acc);
  acc = acc > 0.f ? acc : 0.f;
  float term = acc * Wfc2[j];
  for (int off = 32; off; off >>= 1) term += __shfl_down(term, off, 64);
  if (j == 0) out[g] = term + bfc2[0];
}

// ---------------- launcher ----------------
extern "C" void kernel_launch(void* const* d_in, const int* in_sizes, int n_in,
                              void* d_out, int out_size, void* d_ws, size_t ws_size,
                              hipStream_t stream)
{
  const float* x      = (const float*)d_in[0];
  const int*   ei     = (const int*)d_in[1];
  const int*   batch  = (const int*)d_in[2];
  const float* fp     = (const float*)d_in[3];
  const float* W1     = (const float*)d_in[4];
  const float* a_src1 = (const float*)d_in[5];
  const float* a_dst1 = (const float*)d_in[6];
  const float* b1     = (const float*)d_in[7];
  const float* W2     = (const float*)d_in[8];
  const float* a_src2 = (const float*)d_in[9];
  const float* a_dst2 = (const float*)d_in[10];
  const float* b2     = (const float*)d_in[11];
  const float* Wfp    = (const float*)d_in[12];
  const float* bfp    = (const float*)d_in[13];
  const float* Wfc1   = (const float*)d_in[14];
  const float* bfc1   = (const float*)d_in[15];
  const float* Wfc2   = (const float*)d_in[16];
  const float* bfc2   = (const float*)d_in[17];
  float* out = (float*)d_out;

  const int NN = in_sizes[0] / 128;    // 100000 nodes
  const int E  = in_sizes[1] / 2;      // 400000 edges
  const int G  = in_sizes[3] / 2048;   // 2048 graphs
  const int FIN = 128, H = 4, C1 = 64, C2 = 128;
  const int HC1 = H * C1;   // 256
  const int HC2 = H * C2;   // 512

  // ---- workspace layout (bytes) ----
  char* base = (char*)d_ws;
  size_t off = 0;
  auto alloc = [&](size_t bytes) { char* p = base + off; off += (bytes + 15) & ~(size_t)15; return p; };
  unsigned short* xb     = (unsigned short*)alloc((size_t)NN * FIN * 2);   // also reused as h2hb
  unsigned short* h1b    = (unsigned short*)alloc((size_t)NN * HC1 * 2);
  unsigned short* agg1b  = (unsigned short*)alloc((size_t)NN * HC1 * 2);
  float*          agg2h  = (float*)alloc((size_t)NN * C2 * 4);
  float*          es1    = (float*)alloc((size_t)NN * H * 4);
  float*          ed1    = (float*)alloc((size_t)NN * H * 4);
  float*          es2    = (float*)alloc((size_t)NN * 4);
  float*          ed2    = (float*)alloc((size_t)NN * 4);
  float*          w1     = (float*)alloc((size_t)E * H * 4);
  float*          wself1 = (float*)alloc((size_t)NN * H * 4);
  float*          w2     = (float*)alloc((size_t)E * 4);
  float*          wself2 = (float*)alloc((size_t)NN * 4);
  float*          pooled = (float*)alloc((size_t)G * HC2 * 4);
  float*          fph    = (float*)alloc((size_t)G * 64 * 4);
  unsigned short* W1T    = (unsigned short*)alloc((size_t)HC1 * FIN * 2);
  unsigned short* W2T    = (unsigned short*)alloc((size_t)HC2 * HC1 * 2);
  int* deg      = (int*)alloc((size_t)NN * 4);
  int* cursor   = (int*)alloc((size_t)NN * 4);
  int* gcnt     = (int*)alloc((size_t)G * 4);
  int* rowptr_n = (int*)alloc(((size_t)NN + 1) * 4);
  int* rowptr_g = (int*)alloc(((size_t)G + 1) * 4);
  int* csr_src  = (int*)alloc((size_t)E * 4);
  int* bsum     = (int*)alloc(128 * 4);
  int* bpre     = (int*)alloc(128 * 4);
  unsigned short* h2hb = xb;   // xb dead after GEMM1

  // ---- conversions (independent of CSR build) ----
  {
    size_t nx = (size_t)NN * FIN;
    cvt_f2b<<<(int)((nx + 255) / 256), 256, 0, stream>>>(x, xb, nx);
    transpose_f2b<<<(FIN * HC1 + 255) / 256, 256, 0, stream>>>(W1, W1T, FIN, HC1);
    transpose_f2b<<<(HC1 * HC2 + 255) / 256, 256, 0, stream>>>(W2, W2T, HC1, HC2);
  }

  // ---- CSR by dst + graph segment ptrs ----
  hipMemsetAsync(deg, 0, sizeof(int) * (2 * (size_t)NN + G), stream);  // deg,cursor,gcnt contiguous
  count_deg<<<(E + 255) / 256, 256, 0, stream>>>(ei, E, deg);
  {
    int nb = (NN + 1023) / 1024;
    scan_p1<<<nb, 256, 0, stream>>>(deg, NN, bsum);
    scan_p2<<<1, 128, 0, stream>>>(bsum, bpre, nb, rowptr_n, NN);
    scan_p3<<<nb, 256, 0, stream>>>(deg, bpre, NN, rowptr_n);
  }
  fill_csr<<<(E + 255) / 256, 256, 0, stream>>>(ei, E, cursor, rowptr_n, csr_src);
  count_graph<<<(NN + 255) / 256, 256, 0, stream>>>(batch, NN, gcnt);
  {
    int nb = (G + 1023) / 1024;
    scan_p1<<<nb, 256, 0, stream>>>(gcnt, G, bsum);
    scan_p2<<<1, 128, 0, stream>>>(bsum, bpre, nb, rowptr_g, G);
    scan_p3<<<nb, 256, 0, stream>>>(gcnt, bpre, G, rowptr_g);
  }

  // ---- conv1: h1 = x@W1 (bf16 MFMA), attention, aggregate(+ELU) -> agg1b (bf16) ----
  {
    dim3 gg(HC1 / 128, (NN + 127) / 128);
    gemm_mfma<1><<<gg, 256, 0, stream>>>(xb, W1T, h1b, NN, HC1, FIN);
  }
  compute_e_b<<<NN, HC1, 0, stream>>>(h1b, a_src1, a_dst1, es1, ed1, H, C1);
  alpha_kernel<<<(NN * H + 255) / 256, 256, 0, stream>>>(es1, ed1, rowptr_n, csr_src,
                                                         w1, wself1, NN, H);
  aggregate_b<1><<<(NN + 7) / 8, 256, 0, stream>>>(h1b, w1, wself1, rowptr_n, csr_src,
                                                   b1, agg1b, NN, H, C1);

  // ---- conv2, head-by-head ----
  for (int hd = 0; hd < H; ++hd) {
    dim3 gg(C2 / 128, (NN + 127) / 128);
    gemm_mfma<1><<<gg, 256, 0, stream>>>(agg1b, W2T + (size_t)hd * C2 * HC1, h2hb, NN, C2, HC1);
    compute_e_b<<<NN, C2, 0, stream>>>(h2hb, a_src2 + (size_t)hd * C2, a_dst2 + (size_t)hd * C2,
                                       es2, ed2, 1, C2);
    alpha_kernel<<<(NN + 255) / 256, 256, 0, stream>>>(es2, ed2, rowptr_n, csr_src,
                                                       w2, wself2, NN, 1);
    aggregate_b<0><<<(NN + 15) / 16, 256, 0, stream>>>(h2hb, w2, wself2, rowptr_n, csr_src,
                                                       b2 + (size_t)hd * C2, agg2h, NN, 1, C2);
    pool_mean_kernel<<<G, C2, 0, stream>>>(agg2h, C2, rowptr_g, pooled + (size_t)hd * C2, HC2);
  }

  // ---- fingerprint MLP + fused head ----
  {
    dim3 gg(1, (G + 63) / 64);
    gemm_tiled<<<gg, 256, 0, stream>>>(fp, Wfp, 64, bfp, fph, 64, G, 64, 2048);
  }
  mlp_head<<<G, 64, 0, stream>>>(pooled, fph, Wfc1, bfc1, Wfc2, bfc2, out);
}

// Round 4
// 680.432 us; speedup vs baseline: 2.9062x; 1.4867x over previous
//
#include <hip/hip_runtime.h>
#include <math.h>

#define NEG_SLOPE 0.2f

typedef __attribute__((ext_vector_type(8))) short bf16x8;   // 8 bf16 (4 VGPRs)
typedef __attribute__((ext_vector_type(4))) short bf16x4;   // 8 bytes
typedef __attribute__((ext_vector_type(4))) float f32x4;    // MFMA acc

__device__ __forceinline__ float b2f(short s) {
  return __uint_as_float(((unsigned int)(unsigned short)s) << 16);
}
__device__ __forceinline__ unsigned short f2b_rne(float f) {
  unsigned int u = __float_as_uint(f);
  u = (u + 0x7FFF + ((u >> 16) & 1)) >> 16;
  return (unsigned short)u;
}

// ---------------- fp32 -> bf16 elementwise ----------------
__global__ void cvt_f2b(const float* __restrict__ in, unsigned short* __restrict__ out, size_t n)
{
  size_t i = (size_t)blockIdx.x * 256 + threadIdx.x;
  size_t stride = (size_t)gridDim.x * 256;
  for (; i < n; i += stride) out[i] = f2b_rne(in[i]);
}

// ---------------- W [K,N] f32 -> WT [N,K] bf16 ----------------
__global__ void transpose_f2b(const float* __restrict__ W, unsigned short* __restrict__ WT,
                              int K, int N)
{
  int idx = blockIdx.x * 256 + threadIdx.x;
  if (idx < K * N) {
    int k = idx / N, n = idx - k * N;
    WT[(size_t)n * K + k] = f2b_rne(W[idx]);
  }
}

// ---------------- MFMA GEMM: C[M,N] = A[M,K] @ B[K,N] ----------------
// A bf16 [M,K] row-major, BT bf16 [N,K] row-major. BM=BN=128, BK=32, 4 waves.
template<int WRITE_BF16>
__global__ __launch_bounds__(256) void gemm_mfma(
    const unsigned short* __restrict__ A, const unsigned short* __restrict__ BT,
    void* __restrict__ Cout, int M, int N, int K)
{
  const int LDT = 40;
  __shared__ unsigned short As[128 * 40];
  __shared__ unsigned short Bs[128 * 40];
  const int tid  = threadIdx.x;
  const int wave = tid >> 6;
  const int lane = tid & 63;
  const int ln   = lane & 15;
  const int quad = lane >> 4;
  const int wr0  = (wave >> 1) * 64;
  const int wc0  = (wave & 1) * 64;
  const int bm   = blockIdx.y * 128;
  const int bn   = blockIdx.x * 128;
  const int srow  = tid >> 2;
  const int skoff = (tid & 3) * 8;

  f32x4 acc[4][4];
  const f32x4 z4 = {0.f, 0.f, 0.f, 0.f};
#pragma unroll
  for (int i = 0; i < 4; ++i)
#pragma unroll
    for (int j = 0; j < 4; ++j) acc[i][j] = z4;

  for (int k0 = 0; k0 < K; k0 += 32) {
#pragma unroll
    for (int p = 0; p < 2; ++p) {
      int r = srow + p * 64;
      bf16x8 va = {0, 0, 0, 0, 0, 0, 0, 0};
      if (bm + r < M)
        va = *(const bf16x8*)(A + (size_t)(bm + r) * K + k0 + skoff);
      *(bf16x8*)(&As[r * LDT + skoff]) = va;
      bf16x8 vb = *(const bf16x8*)(BT + (size_t)(bn + r) * K + k0 + skoff);
      *(bf16x8*)(&Bs[r * LDT + skoff]) = vb;
    }
    __syncthreads();
    bf16x8 af[4], bfv[4];
#pragma unroll
    for (int i = 0; i < 4; ++i)
      af[i] = *(const bf16x8*)(&As[(wr0 + i * 16 + ln) * LDT + quad * 8]);
#pragma unroll
    for (int j = 0; j < 4; ++j)
      bfv[j] = *(const bf16x8*)(&Bs[(wc0 + j * 16 + ln) * LDT + quad * 8]);
#pragma unroll
    for (int i = 0; i < 4; ++i)
#pragma unroll
      for (int j = 0; j < 4; ++j)
        acc[i][j] = __builtin_amdgcn_mfma_f32_16x16x32_bf16(af[i], bfv[j], acc[i][j], 0, 0, 0);
    __syncthreads();
  }
#pragma unroll
  for (int i = 0; i < 4; ++i) {
#pragma unroll
    for (int r = 0; r < 4; ++r) {
      int row = bm + wr0 + i * 16 + quad * 4 + r;
      if (row >= M) continue;
#pragma unroll
      for (int j = 0; j < 4; ++j) {
        int col = bn + wc0 + j * 16 + ln;
        float v = acc[i][j][r];
        if (WRITE_BF16)
          ((unsigned short*)Cout)[(size_t)row * N + col] = f2b_rne(v);
        else
          ((float*)Cout)[(size_t)row * N + col] = v;
      }
    }
  }
}

// ---------------- CSR build ----------------
__global__ void count_deg(const int* __restrict__ ei, int E, int* __restrict__ deg)
{
  int e = blockIdx.x * 256 + threadIdx.x;
  if (e < E) atomicAdd(&deg[ei[E + e]], 1);
}

__global__ void fill_csr(const int* __restrict__ ei, int E, int* __restrict__ cursor,
                         const int* __restrict__ rowptr, int* __restrict__ csr_src)
{
  int e = blockIdx.x * 256 + threadIdx.x;
  if (e < E) {
    int d = ei[E + e];
    int pos = atomicAdd(&cursor[d], 1);
    csr_src[rowptr[d] + pos] = ei[e];
  }
}

__global__ void count_graph(const int* __restrict__ batch, int N, int* __restrict__ gcnt)
{
  int i = blockIdx.x * 256 + threadIdx.x;
  if (i < N) atomicAdd(&gcnt[batch[i]], 1);
}

// ---------------- 3-phase exclusive scan ----------------
__global__ void scan_p1(const int* __restrict__ vals, int n, int* __restrict__ bsum)
{
  __shared__ int red[256];
  int base = blockIdx.x * 1024;
  int t = threadIdx.x;
  int s = 0;
#pragma unroll
  for (int i = 0; i < 4; ++i) {
    int idx = base + i * 256 + t;
    if (idx < n) s += vals[idx];
  }
  red[t] = s;
  __syncthreads();
  for (int off = 128; off; off >>= 1) {
    if (t < off) red[t] += red[t + off];
    __syncthreads();
  }
  if (t == 0) bsum[blockIdx.x] = red[0];
}

__global__ void scan_p2(const int* __restrict__ bsum, int* __restrict__ bpre,
                        int nb, int* __restrict__ rowptr, int n)
{
  __shared__ int tmp[128];
  int t = threadIdx.x;
  int v = (t < nb) ? bsum[t] : 0;
  tmp[t] = v;
  __syncthreads();
  for (int off = 1; off < 128; off <<= 1) {
    int add = (t >= off) ? tmp[t - off] : 0;
    __syncthreads();
    tmp[t] += add;
    __syncthreads();
  }
  if (t < nb) bpre[t] = tmp[t] - v;
  if (t == 127) rowptr[n] = tmp[127];
}

__global__ void scan_p3(const int* __restrict__ vals, const int* __restrict__ bpre,
                        int n, int* __restrict__ rowptr)
{
  __shared__ int tmp[256];
  int t = threadIdx.x;
  int base = blockIdx.x * 1024 + t * 4;
  int v[4]; int s = 0;
#pragma unroll
  for (int i = 0; i < 4; ++i) {
    int idx = base + i;
    v[i] = (idx < n) ? vals[idx] : 0;
    s += v[i];
  }
  tmp[t] = s;
  __syncthreads();
  for (int off = 1; off < 256; off <<= 1) {
    int add = (t >= off) ? tmp[t - off] : 0;
    __syncthreads();
    tmp[t] += add;
    __syncthreads();
  }
  int run = bpre[blockIdx.x] + tmp[t] - s;
#pragma unroll
  for (int i = 0; i < 4; ++i) {
    int idx = base + i;
    if (idx < n) rowptr[idx] = run;
    run += v[i];
  }
}

// ---------------- vectorized e_src/e_dst: bf16x8 per lane, shfl-reduce per head ----------------
__global__ __launch_bounds__(256) void compute_e_v(
    const unsigned short* __restrict__ h,
    const float* __restrict__ a_src, const float* __restrict__ a_dst,
    float* __restrict__ es, float* __restrict__ ed,
    int N, int nh, int C)
{
  const int HC = nh * C;
  const int LPN = HC >> 3;                 // lanes per node (32 or 64)
  const int npb = 256 / LPN;
  const int node = blockIdx.x * npb + threadIdx.x / LPN;
  const int lane = threadIdx.x % LPN;
  if (node >= N) return;
  const int ch = lane << 3;
  bf16x8 hv = *(const bf16x8*)(h + (size_t)node * HC + ch);
  float ps = 0.f, pd = 0.f;
#pragma unroll
  for (int r = 0; r < 8; ++r) {
    float f = b2f(hv[r]);
    ps = fmaf(f, a_src[ch + r], ps);
    pd = fmaf(f, a_dst[ch + r], pd);
  }
  const int L = C >> 3;                    // lanes per head (8 or 16)
  for (int off = L >> 1; off; off >>= 1) {
    ps += __shfl_down(ps, off, L);
    pd += __shfl_down(pd, off, L);
  }
  if ((lane & (L - 1)) == 0) {
    int head = lane / L;
    es[(size_t)node * nh + head] = ps;
    ed[(size_t)node * nh + head] = pd;
  }
}

// ---------------- normalized attention weights ----------------
__global__ void alpha_kernel(const float* __restrict__ es, const float* __restrict__ ed,
                             const int* __restrict__ rowptr, const int* __restrict__ csr_src,
                             float* __restrict__ w_csr, float* __restrict__ wself,
                             int N, int nh)
{
  int idx = blockIdx.x * 256 + threadIdx.x;
  if (idx >= N * nh) return;
  const int dst = idx / nh;
  const int h = idx - dst * nh;
  const float edh = ed[(size_t)dst * nh + h];
  const int beg = rowptr[dst], end = rowptr[dst + 1];
  float sum = 0.f;
  for (int e = beg; e < end; ++e) {
    int s = csr_src[e];
    float l = es[(size_t)s * nh + h] + edh;
    l = l >= 0.f ? l : NEG_SLOPE * l;
    float w = expf(l);
    w_csr[(size_t)e * nh + h] = w;
    sum += w;
  }
  float ls = es[(size_t)dst * nh + h] + edh;
  ls = ls >= 0.f ? ls : NEG_SLOPE * ls;
  float wsl = expf(ls);
  sum += wsl;
  const float inv = 1.0f / sum;
  for (int e = beg; e < end; ++e) w_csr[(size_t)e * nh + h] *= inv;
  wself[(size_t)dst * nh + h] = wsl * inv;
}

// ---------------- weighted gather aggregation + bias + ELU, bf16 h -> bf16 out ----------------
__global__ __launch_bounds__(256) void aggregate_b(
    const unsigned short* __restrict__ h,
    const float* __restrict__ w_csr, const float* __restrict__ wself,
    const int* __restrict__ rowptr, const int* __restrict__ csr_src,
    const float* __restrict__ bias, unsigned short* __restrict__ out,
    int N, int nh, int C)
{
  const int HC = nh * C;
  const int CH8 = HC >> 3;
  const int dpb = 256 / CH8;
  const int grp = threadIdx.x / CH8;
  const int lane = threadIdx.x - grp * CH8;
  const int dst = blockIdx.x * dpb + grp;
  if (dst >= N) return;
  const int ch = lane << 3;
  const int head = ch / C;
  const int beg = rowptr[dst], end = rowptr[dst + 1];
  float acc[8] = {0.f, 0.f, 0.f, 0.f, 0.f, 0.f, 0.f, 0.f};
  for (int e = beg; e < end; ++e) {
    int s = csr_src[e];
    float a = w_csr[(size_t)e * nh + head];
    bf16x8 hv = *(const bf16x8*)(h + (size_t)s * HC + ch);
#pragma unroll
    for (int r = 0; r < 8; ++r) acc[r] = fmaf(a, b2f(hv[r]), acc[r]);
  }
  {
    float a = wself[(size_t)dst * nh + head];
    bf16x8 hv = *(const bf16x8*)(h + (size_t)dst * HC + ch);
#pragma unroll
    for (int r = 0; r < 8; ++r) acc[r] = fmaf(a, b2f(hv[r]), acc[r]);
  }
  bf16x8 o;
#pragma unroll
  for (int r = 0; r < 8; ++r) {
    float v = acc[r] + bias[ch + r];
    v = v > 0.f ? v : (expf(v) - 1.0f);
    o[r] = (short)f2b_rne(v);
  }
  *(bf16x8*)(out + (size_t)dst * HC + ch) = o;
}

// ---------------- per-graph mean pool (bf16 in, 4 ch per thread) ----------------
__global__ void pool_mean_b4(const unsigned short* __restrict__ h, int in_stride,
                             const int* __restrict__ grp,
                             float* __restrict__ pooled, int out_stride)
{
  const int g = blockIdx.x;
  const int ch = threadIdx.x * 4;
  const int beg = grp[g], end = grp[g + 1];
  float4 acc = make_float4(0.f, 0.f, 0.f, 0.f);
  for (int i = beg; i < end; ++i) {
    bf16x4 v = *(const bf16x4*)(h + (size_t)i * in_stride + ch);
    acc.x += b2f(v[0]); acc.y += b2f(v[1]);
    acc.z += b2f(v[2]); acc.w += b2f(v[3]);
  }
  float inv = 1.0f / (float)max(end - beg, 1);
  acc.x *= inv; acc.y *= inv; acc.z *= inv; acc.w *= inv;
  *(float4*)(pooled + (size_t)g * out_stride + ch) = acc;
}

// ---------------- fingerprint GEMM: fph[G,64] = fp[G,2048] @ Wfp + bfp ----------------
// one block per graph, 4-way split-K, LDS reduce
__global__ __launch_bounds__(256) void fp_gemm(
    const float* __restrict__ fp, const float* __restrict__ Wfp,
    const float* __restrict__ bfp, float* __restrict__ fph, int K)
{
  const int g = blockIdx.x;
  const int j = threadIdx.x & 63;
  const int s = threadIdx.x >> 6;
  const int kb = s * (K >> 2);
  const float* fpr = fp + (size_t)g * K;
  float a0 = 0.f, a1 = 0.f, a2 = 0.f, a3 = 0.f;
  for (int k = 0; k < (K >> 2); k += 4) {
    float4 fv = *(const float4*)(fpr + kb + k);
    a0 = fmaf(fv.x, Wfp[(size_t)(kb + k + 0) * 64 + j], a0);
    a1 = fmaf(fv.y, Wfp[(size_t)(kb + k + 1) * 64 + j], a1);
    a2 = fmaf(fv.z, Wfp[(size_t)(kb + k + 2) * 64 + j], a2);
    a3 = fmaf(fv.w, Wfp[(size_t)(kb + k + 3) * 64 + j], a3);
  }
  __shared__ float red[256];
  red[threadIdx.x] = (a0 + a1) + (a2 + a3);
  __syncthreads();
  if (s == 0)
    fph[(size_t)g * 64 + j] = red[j] + red[64 + j] + red[128 + j] + red[192 + j] + bfp[j];
}

// ---------------- fused fc1(relu) + fc2 head ----------------
__global__ void mlp_head(const float* __restrict__ pooled, const float* __restrict__ fph,
                         const float* __restrict__ Wfc1, const float* __restrict__ bfc1,
                         const float* __restrict__ Wfc2, const float* __restrict__ bfc2,
                         float* __restrict__ out)
{
  const int g = blockIdx.x;
  const int j = threadIdx.x;
  float acc = bfc1[j];
  const float* pz = pooled + (size_t)g * 512;
  for (int k = 0; k < 512; ++k) acc = fmaf(pz[k], Wfc1[k * 64 + j], acc);
  const float* pf = fph + (size_t)g * 64;
  for (int k = 0; k < 64; ++k) acc = fmaf(pf[k], Wfc1[(512 + k) * 64 + j], acc);
  acc = acc > 0.f ? acc : 0.f;
  float term = acc * Wfc2[j];
  for (int off = 32; off; off >>= 1) term += __shfl_down(term, off, 64);
  if (j == 0) out[g] = term + bfc2[0];
}

// ---------------- launcher ----------------
extern "C" void kernel_launch(void* const* d_in, const int* in_sizes, int n_in,
                              void* d_out, int out_size, void* d_ws, size_t ws_size,
                              hipStream_t stream)
{
  const float* x      = (const float*)d_in[0];
  const int*   ei     = (const int*)d_in[1];
  const int*   batch  = (const int*)d_in[2];
  const float* fp     = (const float*)d_in[3];
  const float* W1     = (const float*)d_in[4];
  const float* a_src1 = (const float*)d_in[5];
  const float* a_dst1 = (const float*)d_in[6];
  const float* b1     = (const float*)d_in[7];
  const float* W2     = (const float*)d_in[8];
  const float* a_src2 = (const float*)d_in[9];
  const float* a_dst2 = (const float*)d_in[10];
  const float* b2     = (const float*)d_in[11];
  const float* Wfp    = (const float*)d_in[12];
  const float* bfp    = (const float*)d_in[13];
  const float* Wfc1   = (const float*)d_in[14];
  const float* bfc1   = (const float*)d_in[15];
  const float* Wfc2   = (const float*)d_in[16];
  const float* bfc2   = (const float*)d_in[17];
  float* out = (float*)d_out;

  const int NN = in_sizes[0] / 128;
  const int E  = in_sizes[1] / 2;
  const int G  = in_sizes[3] / 2048;
  const int FIN = 128, H = 4, C1 = 64, C2 = 128;
  const int HC1 = H * C1;   // 256
  const int HC2 = H * C2;   // 512

  // ---- workspace layout; conv2 partition count chosen from ws_size ----
  unsigned short *xb, *h1b, *h2b, *agg1b, *agg2b, *W1T, *W2T;
  float *es1, *ed1, *wself1, *w1, *es2, *ed2, *wself2, *w2, *pooled, *fph;
  int *deg, *cursor, *gcnt, *rowptr_n, *rowptr_g, *csr_src, *bsum, *bpre;

  auto build = [&](int npart) -> size_t {
    const int Cpart = HC2 / npart;
    char* base = (char*)d_ws;
    size_t off = 0;
    auto alloc = [&](size_t bytes) {
      char* p = base + off; off += (bytes + 15) & ~(size_t)15; return p;
    };
    // R0: xb + h1b (early) overlapped with h2b (late)
    size_t xb_sz  = ((size_t)NN * FIN * 2 + 15) & ~(size_t)15;
    size_t h1b_sz = ((size_t)NN * HC1 * 2 + 15) & ~(size_t)15;
    size_t h2b_sz = ((size_t)NN * Cpart * 2 + 15) & ~(size_t)15;
    size_t r0_sz  = xb_sz + h1b_sz; if (h2b_sz > r0_sz) r0_sz = h2b_sz;
    char* R0 = alloc(r0_sz);
    xb  = (unsigned short*)R0;
    h1b = (unsigned short*)(R0 + xb_sz);
    h2b = (unsigned short*)R0;
    agg1b  = (unsigned short*)alloc((size_t)NN * HC1 * 2);
    agg2b  = (unsigned short*)alloc((size_t)NN * Cpart * 2);
    es1    = (float*)alloc((size_t)NN * H * 4);
    ed1    = (float*)alloc((size_t)NN * H * 4);
    wself1 = (float*)alloc((size_t)NN * H * 4);
    w1     = (float*)alloc((size_t)E * H * 4);
    es2    = (float*)alloc((size_t)NN * H * 4);
    ed2    = (float*)alloc((size_t)NN * H * 4);
    wself2 = (float*)alloc((size_t)NN * H * 4);
    w2     = (float*)alloc((size_t)E * H * 4);
    pooled = (float*)alloc((size_t)G * HC2 * 4);
    fph    = (float*)alloc((size_t)G * 64 * 4);
    W1T    = (unsigned short*)alloc((size_t)HC1 * FIN * 2);
    W2T    = (unsigned short*)alloc((size_t)HC2 * HC1 * 2);
    deg      = (int*)alloc((size_t)NN * 4);
    cursor   = (int*)alloc((size_t)NN * 4);
    gcnt     = (int*)alloc((size_t)G * 4);
    rowptr_n = (int*)alloc(((size_t)NN + 1) * 4);
    rowptr_g = (int*)alloc(((size_t)G + 1) * 4);
    csr_src  = (int*)alloc((size_t)E * 4);
    bsum     = (int*)alloc(128 * 4);
    bpre     = (int*)alloc(128 * 4);
    return off;
  };
  int npart = 1;
  if (build(1) > ws_size) { npart = 2; build(2); }
  const int HP = H / npart;        // heads per partition
  const int Cpart = HP * C2;       // channels per partition (512 or 256)

  // ---- conversions ----
  {
    size_t nx = (size_t)NN * FIN;
    cvt_f2b<<<(int)((nx + 255) / 256), 256, 0, stream>>>(x, xb, nx);
    transpose_f2b<<<(FIN * HC1 + 255) / 256, 256, 0, stream>>>(W1, W1T, FIN, HC1);
    transpose_f2b<<<(HC1 * HC2 + 255) / 256, 256, 0, stream>>>(W2, W2T, HC1, HC2);
  }

  // ---- CSR by dst + graph segment ptrs ----
  hipMemsetAsync(deg, 0, sizeof(int) * (2 * (size_t)NN + G), stream);
  count_deg<<<(E + 255) / 256, 256, 0, stream>>>(ei, E, deg);
  {
    int nb = (NN + 1023) / 1024;
    scan_p1<<<nb, 256, 0, stream>>>(deg, NN, bsum);
    scan_p2<<<1, 128, 0, stream>>>(bsum, bpre, nb, rowptr_n, NN);
    scan_p3<<<nb, 256, 0, stream>>>(deg, bpre, NN, rowptr_n);
  }
  fill_csr<<<(E + 255) / 256, 256, 0, stream>>>(ei, E, cursor, rowptr_n, csr_src);
  count_graph<<<(NN + 255) / 256, 256, 0, stream>>>(batch, NN, gcnt);
  {
    int nb = (G + 1023) / 1024;
    scan_p1<<<nb, 256, 0, stream>>>(gcnt, G, bsum);
    scan_p2<<<1, 128, 0, stream>>>(bsum, bpre, nb, rowptr_g, G);
    scan_p3<<<nb, 256, 0, stream>>>(gcnt, bpre, G, rowptr_g);
  }

  // ---- conv1 ----
  {
    dim3 gg(HC1 / 128, (NN + 127) / 128);
    gemm_mfma<1><<<gg, 256, 0, stream>>>(xb, W1T, h1b, NN, HC1, FIN);
  }
  compute_e_v<<<(NN + 7) / 8, 256, 0, stream>>>(h1b, a_src1, a_dst1, es1, ed1, NN, H, C1);
  alpha_kernel<<<(NN * H + 255) / 256, 256, 0, stream>>>(es1, ed1, rowptr_n, csr_src,
                                                         w1, wself1, NN, H);
  aggregate_b<<<(NN + 7) / 8, 256, 0, stream>>>(h1b, w1, wself1, rowptr_n, csr_src,
                                                b1, agg1b, NN, H, C1);

  // ---- conv2, by partition (npart=1: all heads fused; npart=2: head pairs) ----
  for (int p = 0; p < npart; ++p) {
    dim3 gg(Cpart / 128, (NN + 127) / 128);
    gemm_mfma<1><<<gg, 256, 0, stream>>>(agg1b, W2T + (size_t)p * Cpart * HC1, h2b,
                                         NN, Cpart, HC1);
    {
      int LPN = (HP * C2) >> 3;           // 64 or 32
      int npb = 256 / LPN;
      compute_e_v<<<(NN + npb - 1) / npb, 256, 0, stream>>>(
          h2b, a_src2 + (size_t)p * Cpart, a_dst2 + (size_t)p * Cpart,
          es2, ed2, NN, HP, C2);
    }
    alpha_kernel<<<(NN * HP + 255) / 256, 256, 0, stream>>>(es2, ed2, rowptr_n, csr_src,
                                                            w2, wself2, NN, HP);
    {
      int CH8 = (HP * C2) >> 3;
      int dpb = 256 / CH8;
      aggregate_b<<<(NN + dpb - 1) / dpb, 256, 0, stream>>>(
          h2b, w2, wself2, rowptr_n, csr_src, b2 + (size_t)p * Cpart, agg2b, NN, HP, C2);
    }
    pool_mean_b4<<<G, Cpart / 4, 0, stream>>>(agg2b, Cpart, rowptr_g,
                                              pooled + (size_t)p * Cpart, HC2);
  }

  // ---- fingerprint GEMM + fused head ----
  fp_gemm<<<G, 256, 0, stream>>>(fp, Wfp, bfp, fph, 2048);
  mlp_head<<<G, 64, 0, stream>>>(pooled, fph, Wfc1, bfc1, Wfc2, bfc2, out);
}

// Round 5
// 630.680 us; speedup vs baseline: 3.1355x; 1.0789x over previous
//
#include <hip/hip_runtime.h>
#include <math.h>

#define NEG_SLOPE 0.2f

typedef __attribute__((ext_vector_type(8))) short bf16x8;   // 8 bf16 (4 VGPRs)
typedef __attribute__((ext_vector_type(4))) short bf16x4;   // 8 bytes
typedef __attribute__((ext_vector_type(4))) float f32x4;    // MFMA acc

__device__ __forceinline__ float b2f(short s) {
  return __uint_as_float(((unsigned int)(unsigned short)s) << 16);
}
__device__ __forceinline__ unsigned short f2b_rne(float f) {
  unsigned int u = __float_as_uint(f);
  u = (u + 0x7FFF + ((u >> 16) & 1)) >> 16;
  return (unsigned short)u;
}

// ---------------- fp32 -> bf16 elementwise ----------------
__global__ void cvt_f2b(const float* __restrict__ in, unsigned short* __restrict__ out, size_t n)
{
  size_t i = (size_t)blockIdx.x * 256 + threadIdx.x;
  size_t stride = (size_t)gridDim.x * 256;
  for (; i < n; i += stride) out[i] = f2b_rne(in[i]);
}

// ---------------- W [K,N] f32 -> WT [N,K] bf16 ----------------
__global__ void transpose_f2b(const float* __restrict__ W, unsigned short* __restrict__ WT,
                              int K, int N)
{
  int idx = blockIdx.x * 256 + threadIdx.x;
  if (idx < K * N) {
    int k = idx / N, n = idx - k * N;
    WT[(size_t)n * K + k] = f2b_rne(W[idx]);
  }
}

// ---------------- MFMA GEMM: C[M,N] = A[M,K] @ B[K,N], BM=BN=128 ----------------
// A bf16 [M,K] row-major, BT bf16 [N,K] row-major. BK=32, 4 waves (2x2 of 64x64).
template<int WRITE_BF16>
__global__ __launch_bounds__(256) void gemm_mfma(
    const unsigned short* __restrict__ A, const unsigned short* __restrict__ BT,
    void* __restrict__ Cout, int M, int N, int K)
{
  const int LDT = 40;
  __shared__ unsigned short As[128 * 40];
  __shared__ unsigned short Bs[128 * 40];
  const int tid  = threadIdx.x;
  const int wave = tid >> 6;
  const int lane = tid & 63;
  const int ln   = lane & 15;
  const int quad = lane >> 4;
  const int wr0  = (wave >> 1) * 64;
  const int wc0  = (wave & 1) * 64;
  const int bm   = blockIdx.y * 128;
  const int bn   = blockIdx.x * 128;
  const int srow  = tid >> 2;
  const int skoff = (tid & 3) * 8;

  f32x4 acc[4][4];
  const f32x4 z4 = {0.f, 0.f, 0.f, 0.f};
#pragma unroll
  for (int i = 0; i < 4; ++i)
#pragma unroll
    for (int j = 0; j < 4; ++j) acc[i][j] = z4;

  for (int k0 = 0; k0 < K; k0 += 32) {
#pragma unroll
    for (int p = 0; p < 2; ++p) {
      int r = srow + p * 64;
      bf16x8 va = {0, 0, 0, 0, 0, 0, 0, 0};
      if (bm + r < M)
        va = *(const bf16x8*)(A + (size_t)(bm + r) * K + k0 + skoff);
      *(bf16x8*)(&As[r * LDT + skoff]) = va;
      bf16x8 vb = *(const bf16x8*)(BT + (size_t)(bn + r) * K + k0 + skoff);
      *(bf16x8*)(&Bs[r * LDT + skoff]) = vb;
    }
    __syncthreads();
    bf16x8 af[4], bfv[4];
#pragma unroll
    for (int i = 0; i < 4; ++i)
      af[i] = *(const bf16x8*)(&As[(wr0 + i * 16 + ln) * LDT + quad * 8]);
#pragma unroll
    for (int j = 0; j < 4; ++j)
      bfv[j] = *(const bf16x8*)(&Bs[(wc0 + j * 16 + ln) * LDT + quad * 8]);
#pragma unroll
    for (int i = 0; i < 4; ++i)
#pragma unroll
      for (int j = 0; j < 4; ++j)
        acc[i][j] = __builtin_amdgcn_mfma_f32_16x16x32_bf16(af[i], bfv[j], acc[i][j], 0, 0, 0);
    __syncthreads();
  }
#pragma unroll
  for (int i = 0; i < 4; ++i) {
#pragma unroll
    for (int r = 0; r < 4; ++r) {
      int row = bm + wr0 + i * 16 + quad * 4 + r;
      if (row >= M) continue;
#pragma unroll
      for (int j = 0; j < 4; ++j) {
        int col = bn + wc0 + j * 16 + ln;
        float v = acc[i][j][r];
        if (WRITE_BF16)
          ((unsigned short*)Cout)[(size_t)row * N + col] = f2b_rne(v);
        else
          ((float*)Cout)[(size_t)row * N + col] = v;
      }
    }
  }
}

// ---------------- skinny MFMA GEMM, N=64, split-K, fp32 partials ----------------
// A bf16 [M,K] (lda=K), BT bf16 [64][K] (ldb=K). grid=(KSPLIT, M/128), 256 thr.
// Cp[ks][M][64] fp32. kchunk % 64 == 0 (except allows kchunk==64). BM=128, BK=64.
// wave w -> rows [w*32, w*32+32), all 64 cols. M % 128 == 0 assumed (M=2048).
__global__ __launch_bounds__(256) void gemm_mfma_n64(
    const unsigned short* __restrict__ A, int lda,
    const unsigned short* __restrict__ BT, int ldb,
    float* __restrict__ Cp, int M, int kchunk)
{
  const int LDT = 72;
  __shared__ unsigned short As[128 * 72];
  __shared__ unsigned short Bs[64 * 72];
  const int tid  = threadIdx.x;
  const int wave = tid >> 6;
  const int lane = tid & 63;
  const int ln   = lane & 15;
  const int quad = lane >> 4;
  const int ks   = blockIdx.x;
  const int bm   = blockIdx.y * 128;
  const int k_beg = ks * kchunk;
  const int k_end = k_beg + kchunk;
  // staging maps
  const int arow = tid >> 1;            // 0..127
  const int akb  = (tid & 1) * 32;      // 0,32
  const int brow = tid >> 2;            // 0..63
  const int bkb  = (tid & 3) * 16;      // 0,16,32,48

  f32x4 acc[2][4];
  const f32x4 z4 = {0.f, 0.f, 0.f, 0.f};
#pragma unroll
  for (int i = 0; i < 2; ++i)
#pragma unroll
    for (int j = 0; j < 4; ++j) acc[i][j] = z4;

  for (int k0 = k_beg; k0 < k_end; k0 += 64) {
    const unsigned short* ap = A + (size_t)(bm + arow) * lda + k0 + akb;
#pragma unroll
    for (int q = 0; q < 4; ++q)
      *(bf16x8*)(&As[arow * LDT + akb + q * 8]) = *(const bf16x8*)(ap + q * 8);
    const unsigned short* bp = BT + (size_t)brow * ldb + k0 + bkb;
#pragma unroll
    for (int q = 0; q < 2; ++q)
      *(bf16x8*)(&Bs[brow * LDT + bkb + q * 8]) = *(const bf16x8*)(bp + q * 8);
    __syncthreads();
#pragma unroll
    for (int kk = 0; kk < 2; ++kk) {
      bf16x8 af[2], bfv[4];
#pragma unroll
      for (int i = 0; i < 2; ++i)
        af[i] = *(const bf16x8*)(&As[(wave * 32 + i * 16 + ln) * LDT + kk * 32 + quad * 8]);
#pragma unroll
      for (int j = 0; j < 4; ++j)
        bfv[j] = *(const bf16x8*)(&Bs[(j * 16 + ln) * LDT + kk * 32 + quad * 8]);
#pragma unroll
      for (int i = 0; i < 2; ++i)
#pragma unroll
        for (int j = 0; j < 4; ++j)
          acc[i][j] = __builtin_amdgcn_mfma_f32_16x16x32_bf16(af[i], bfv[j], acc[i][j], 0, 0, 0);
    }
    __syncthreads();
  }
#pragma unroll
  for (int i = 0; i < 2; ++i)
#pragma unroll
    for (int r = 0; r < 4; ++r) {
      int row = bm + wave * 32 + i * 16 + quad * 4 + r;
#pragma unroll
      for (int j = 0; j < 4; ++j)
        Cp[((size_t)ks * M + row) * 64 + j * 16 + ln] = acc[i][j][r];
    }
}

// ---------------- fp partial reduce + bias -> bf16 into z cols [512,576) ----------------
__global__ void fp_finish(const float* __restrict__ Cp, int ksplit, int M,
                          const float* __restrict__ bfp,
                          unsigned short* __restrict__ zb)
{
  const int g = blockIdx.x;
  const int j = threadIdx.x;
  float s = bfp[j];
  for (int ks = 0; ks < ksplit; ++ks) s += Cp[((size_t)ks * M + g) * 64 + j];
  zb[(size_t)g * 576 + 512 + j] = f2b_rne(s);
}

// ---------------- mlp partial reduce + bias + relu + fc2 dot -> out ----------------
__global__ void mlp_finish(const float* __restrict__ Cp, int ksplit, int M,
                           const float* __restrict__ bfc1,
                           const float* __restrict__ Wfc2, const float* __restrict__ bfc2,
                           float* __restrict__ out)
{
  const int g = blockIdx.x;
  const int j = threadIdx.x;
  float s = bfc1[j];
  for (int ks = 0; ks < ksplit; ++ks) s += Cp[((size_t)ks * M + g) * 64 + j];
  s = s > 0.f ? s : 0.f;
  float term = s * Wfc2[j];
  for (int off = 32; off; off >>= 1) term += __shfl_down(term, off, 64);
  if (j == 0) out[g] = term + bfc2[0];
}

// ---------------- CSR build ----------------
__global__ void count_deg(const int* __restrict__ ei, int E, int* __restrict__ deg)
{
  int e = blockIdx.x * 256 + threadIdx.x;
  if (e < E) atomicAdd(&deg[ei[E + e]], 1);
}

__global__ void fill_csr(const int* __restrict__ ei, int E, int* __restrict__ cursor,
                         const int* __restrict__ rowptr, int* __restrict__ csr_src)
{
  int e = blockIdx.x * 256 + threadIdx.x;
  if (e < E) {
    int d = ei[E + e];
    int pos = atomicAdd(&cursor[d], 1);
    csr_src[rowptr[d] + pos] = ei[e];
  }
}

__global__ void count_graph(const int* __restrict__ batch, int N, int* __restrict__ gcnt)
{
  int i = blockIdx.x * 256 + threadIdx.x;
  if (i < N) atomicAdd(&gcnt[batch[i]], 1);
}

// ---------------- 3-phase exclusive scan ----------------
__global__ void scan_p1(const int* __restrict__ vals, int n, int* __restrict__ bsum)
{
  __shared__ int red[256];
  int base = blockIdx.x * 1024;
  int t = threadIdx.x;
  int s = 0;
#pragma unroll
  for (int i = 0; i < 4; ++i) {
    int idx = base + i * 256 + t;
    if (idx < n) s += vals[idx];
  }
  red[t] = s;
  __syncthreads();
  for (int off = 128; off; off >>= 1) {
    if (t < off) red[t] += red[t + off];
    __syncthreads();
  }
  if (t == 0) bsum[blockIdx.x] = red[0];
}

__global__ void scan_p2(const int* __restrict__ bsum, int* __restrict__ bpre,
                        int nb, int* __restrict__ rowptr, int n)
{
  __shared__ int tmp[128];
  int t = threadIdx.x;
  int v = (t < nb) ? bsum[t] : 0;
  tmp[t] = v;
  __syncthreads();
  for (int off = 1; off < 128; off <<= 1) {
    int add = (t >= off) ? tmp[t - off] : 0;
    __syncthreads();
    tmp[t] += add;
    __syncthreads();
  }
  if (t < nb) bpre[t] = tmp[t] - v;
  if (t == 127) rowptr[n] = tmp[127];
}

__global__ void scan_p3(const int* __restrict__ vals, const int* __restrict__ bpre,
                        int n, int* __restrict__ rowptr)
{
  __shared__ int tmp[256];
  int t = threadIdx.x;
  int base = blockIdx.x * 1024 + t * 4;
  int v[4]; int s = 0;
#pragma unroll
  for (int i = 0; i < 4; ++i) {
    int idx = base + i;
    v[i] = (idx < n) ? vals[idx] : 0;
    s += v[i];
  }
  tmp[t] = s;
  __syncthreads();
  for (int off = 1; off < 256; off <<= 1) {
    int add = (t >= off) ? tmp[t - off] : 0;
    __syncthreads();
    tmp[t] += add;
    __syncthreads();
  }
  int run = bpre[blockIdx.x] + tmp[t] - s;
#pragma unroll
  for (int i = 0; i < 4; ++i) {
    int idx = base + i;
    if (idx < n) rowptr[idx] = run;
    run += v[i];
  }
}

// ---------------- vectorized e_src/e_dst ----------------
__global__ __launch_bounds__(256) void compute_e_v(
    const unsigned short* __restrict__ h,
    const float* __restrict__ a_src, const float* __restrict__ a_dst,
    float* __restrict__ es, float* __restrict__ ed,
    int N, int nh, int C)
{
  const int HC = nh * C;
  const int LPN = HC >> 3;
  const int npb = 256 / LPN;
  const int node = blockIdx.x * npb + threadIdx.x / LPN;
  const int lane = threadIdx.x % LPN;
  if (node >= N) return;
  const int ch = lane << 3;
  bf16x8 hv = *(const bf16x8*)(h + (size_t)node * HC + ch);
  float ps = 0.f, pd = 0.f;
#pragma unroll
  for (int r = 0; r < 8; ++r) {
    float f = b2f(hv[r]);
    ps = fmaf(f, a_src[ch + r], ps);
    pd = fmaf(f, a_dst[ch + r], pd);
  }
  const int L = C >> 3;
  for (int off = L >> 1; off; off >>= 1) {
    ps += __shfl_down(ps, off, L);
    pd += __shfl_down(pd, off, L);
  }
  if ((lane & (L - 1)) == 0) {
    int head = lane / L;
    es[(size_t)node * nh + head] = ps;
    ed[(size_t)node * nh + head] = pd;
  }
}

// ---------------- normalized attention weights ----------------
__global__ void alpha_kernel(const float* __restrict__ es, const float* __restrict__ ed,
                             const int* __restrict__ rowptr, const int* __restrict__ csr_src,
                             float* __restrict__ w_csr, float* __restrict__ wself,
                             int N, int nh)
{
  int idx = blockIdx.x * 256 + threadIdx.x;
  if (idx >= N * nh) return;
  const int dst = idx / nh;
  const int h = idx - dst * nh;
  const float edh = ed[(size_t)dst * nh + h];
  const int beg = rowptr[dst], end = rowptr[dst + 1];
  float sum = 0.f;
  for (int e = beg; e < end; ++e) {
    int s = csr_src[e];
    float l = es[(size_t)s * nh + h] + edh;
    l = l >= 0.f ? l : NEG_SLOPE * l;
    float w = expf(l);
    w_csr[(size_t)e * nh + h] = w;
    sum += w;
  }
  float ls = es[(size_t)dst * nh + h] + edh;
  ls = ls >= 0.f ? ls : NEG_SLOPE * ls;
  float wsl = expf(ls);
  sum += wsl;
  const float inv = 1.0f / sum;
  for (int e = beg; e < end; ++e) w_csr[(size_t)e * nh + h] *= inv;
  wself[(size_t)dst * nh + h] = wsl * inv;
}

// ---------------- weighted gather aggregation + bias + ELU ----------------
__global__ __launch_bounds__(256) void aggregate_b(
    const unsigned short* __restrict__ h,
    const float* __restrict__ w_csr, const float* __restrict__ wself,
    const int* __restrict__ rowptr, const int* __restrict__ csr_src,
    const float* __restrict__ bias, unsigned short* __restrict__ out,
    int N, int nh, int C)
{
  const int HC = nh * C;
  const int CH8 = HC >> 3;
  const int dpb = 256 / CH8;
  const int grp = threadIdx.x / CH8;
  const int lane = threadIdx.x - grp * CH8;
  const int dst = blockIdx.x * dpb + grp;
  if (dst >= N) return;
  const int ch = lane << 3;
  const int head = ch / C;
  const int beg = rowptr[dst], end = rowptr[dst + 1];
  float acc[8] = {0.f, 0.f, 0.f, 0.f, 0.f, 0.f, 0.f, 0.f};
  for (int e = beg; e < end; ++e) {
    int s = csr_src[e];
    float a = w_csr[(size_t)e * nh + head];
    bf16x8 hv = *(const bf16x8*)(h + (size_t)s * HC + ch);
#pragma unroll
    for (int r = 0; r < 8; ++r) acc[r] = fmaf(a, b2f(hv[r]), acc[r]);
  }
  {
    float a = wself[(size_t)dst * nh + head];
    bf16x8 hv = *(const bf16x8*)(h + (size_t)dst * HC + ch);
#pragma unroll
    for (int r = 0; r < 8; ++r) acc[r] = fmaf(a, b2f(hv[r]), acc[r]);
  }
  bf16x8 o;
#pragma unroll
  for (int r = 0; r < 8; ++r) {
    float v = acc[r] + bias[ch + r];
    v = v > 0.f ? v : (expf(v) - 1.0f);
    o[r] = (short)f2b_rne(v);
  }
  *(bf16x8*)(out + (size_t)dst * HC + ch) = o;
}

// ---------------- per-graph mean pool -> bf16 into z (stride 576) ----------------
__global__ void pool_mean_zb(const unsigned short* __restrict__ h, int in_stride,
                             const int* __restrict__ grp,
                             unsigned short* __restrict__ zb, int col_off)
{
  const int g = blockIdx.x;
  const int ch = threadIdx.x * 4;
  const int beg = grp[g], end = grp[g + 1];
  float4 acc = make_float4(0.f, 0.f, 0.f, 0.f);
  for (int i = beg; i < end; ++i) {
    bf16x4 v = *(const bf16x4*)(h + (size_t)i * in_stride + ch);
    acc.x += b2f(v[0]); acc.y += b2f(v[1]);
    acc.z += b2f(v[2]); acc.w += b2f(v[3]);
  }
  float inv = 1.0f / (float)max(end - beg, 1);
  bf16x4 o;
  o[0] = (short)f2b_rne(acc.x * inv);
  o[1] = (short)f2b_rne(acc.y * inv);
  o[2] = (short)f2b_rne(acc.z * inv);
  o[3] = (short)f2b_rne(acc.w * inv);
  *(bf16x4*)(zb + (size_t)g * 576 + col_off + ch) = o;
}

// ---------------- launcher ----------------
extern "C" void kernel_launch(void* const* d_in, const int* in_sizes, int n_in,
                              void* d_out, int out_size, void* d_ws, size_t ws_size,
                              hipStream_t stream)
{
  const float* x      = (const float*)d_in[0];
  const int*   ei     = (const int*)d_in[1];
  const int*   batch  = (const int*)d_in[2];
  const float* fp     = (const float*)d_in[3];
  const float* W1     = (const float*)d_in[4];
  const float* a_src1 = (const float*)d_in[5];
  const float* a_dst1 = (const float*)d_in[6];
  const float* b1     = (const float*)d_in[7];
  const float* W2     = (const float*)d_in[8];
  const float* a_src2 = (const float*)d_in[9];
  const float* a_dst2 = (const float*)d_in[10];
  const float* b2     = (const float*)d_in[11];
  const float* Wfp    = (const float*)d_in[12];
  const float* bfp    = (const float*)d_in[13];
  const float* Wfc1   = (const float*)d_in[14];
  const float* bfc1   = (const float*)d_in[15];
  const float* Wfc2   = (const float*)d_in[16];
  const float* bfc2   = (const float*)d_in[17];
  float* out = (float*)d_out;

  const int NN = in_sizes[0] / 128;
  const int E  = in_sizes[1] / 2;
  const int G  = in_sizes[3] / 2048;
  const int FIN = 128, H = 4, C1 = 64, C2 = 128;
  const int HC1 = H * C1;   // 256
  const int HC2 = H * C2;   // 512
  const int KFP = in_sizes[3] / G;   // 2048
  const int KZ  = HC2 + 64;          // 576
  const int KS_FP = 16;              // fp split-K (chunk 128)
  const int KS_Z  = 9;               // mlp split-K (chunk 64)

  // ---- workspace layout; conv2 partition count chosen from ws_size ----
  unsigned short *xb, *h1b, *h2b, *agg1b, *agg2b, *W1T, *W2T;
  unsigned short *fpb, *WfpT, *Wfc1T, *zb;
  float *es1, *ed1, *wself1, *w1, *es2, *ed2, *wself2, *w2, *Cp_fp, *Cp_z;
  int *deg, *cursor, *gcnt, *rowptr_n, *rowptr_g, *csr_src, *bsum, *bpre;

  auto build = [&](int npart) -> size_t {
    const int Cpart = HC2 / npart;
    char* base = (char*)d_ws;
    size_t off = 0;
    auto alloc = [&](size_t bytes) {
      char* p = base + off; off += (bytes + 15) & ~(size_t)15; return p;
    };
    size_t xb_sz  = ((size_t)NN * FIN * 2 + 15) & ~(size_t)15;
    size_t h1b_sz = ((size_t)NN * HC1 * 2 + 15) & ~(size_t)15;
    size_t h2b_sz = ((size_t)NN * Cpart * 2 + 15) & ~(size_t)15;
    size_t r0_sz  = xb_sz + h1b_sz; if (h2b_sz > r0_sz) r0_sz = h2b_sz;
    char* R0 = alloc(r0_sz);
    xb  = (unsigned short*)R0;
    h1b = (unsigned short*)(R0 + xb_sz);
    h2b = (unsigned short*)R0;
    agg1b  = (unsigned short*)alloc((size_t)NN * HC1 * 2);
    agg2b  = (unsigned short*)alloc((size_t)NN * Cpart * 2);
    es1    = (float*)alloc((size_t)NN * H * 4);
    ed1    = (float*)alloc((size_t)NN * H * 4);
    wself1 = (float*)alloc((size_t)NN * H * 4);
    w1     = (float*)alloc((size_t)E * H * 4);
    es2    = (float*)alloc((size_t)NN * H * 4);
    ed2    = (float*)alloc((size_t)NN * H * 4);
    wself2 = (float*)alloc((size_t)NN * H * 4);
    w2     = (float*)alloc((size_t)E * H * 4);
    zb     = (unsigned short*)alloc((size_t)G * KZ * 2);
    fpb    = (unsigned short*)alloc((size_t)G * KFP * 2);
    WfpT   = (unsigned short*)alloc((size_t)64 * KFP * 2);
    Wfc1T  = (unsigned short*)alloc((size_t)64 * KZ * 2);
    Cp_fp  = (float*)alloc((size_t)KS_FP * G * 64 * 4);
    Cp_z   = (float*)alloc((size_t)KS_Z * G * 64 * 4);
    W1T    = (unsigned short*)alloc((size_t)HC1 * FIN * 2);
    W2T    = (unsigned short*)alloc((size_t)HC2 * HC1 * 2);
    deg      = (int*)alloc((size_t)NN * 4);
    cursor   = (int*)alloc((size_t)NN * 4);
    gcnt     = (int*)alloc((size_t)G * 4);
    rowptr_n = (int*)alloc(((size_t)NN + 1) * 4);
    rowptr_g = (int*)alloc(((size_t)G + 1) * 4);
    csr_src  = (int*)alloc((size_t)E * 4);
    bsum     = (int*)alloc(128 * 4);
    bpre     = (int*)alloc(128 * 4);
    return off;
  };
  int npart = 1;
  if (build(1) > ws_size) { npart = 2; build(2); }
  const int HP = H / npart;
  const int Cpart = HP * C2;

  // ---- conversions ----
  {
    size_t nx = (size_t)NN * FIN;
    cvt_f2b<<<(int)((nx + 255) / 256), 256, 0, stream>>>(x, xb, nx);
    size_t nf = (size_t)G * KFP;
    cvt_f2b<<<2048, 256, 0, stream>>>(fp, fpb, nf);
    transpose_f2b<<<(FIN * HC1 + 255) / 256, 256, 0, stream>>>(W1, W1T, FIN, HC1);
    transpose_f2b<<<(HC1 * HC2 + 255) / 256, 256, 0, stream>>>(W2, W2T, HC1, HC2);
    transpose_f2b<<<(KFP * 64 + 255) / 256, 256, 0, stream>>>(Wfp, WfpT, KFP, 64);
    transpose_f2b<<<(KZ * 64 + 255) / 256, 256, 0, stream>>>(Wfc1, Wfc1T, KZ, 64);
  }

  // ---- fingerprint branch: fpb @ WfpT -> zb cols [512,576) ----
  {
    dim3 gg(KS_FP, G / 128);
    gemm_mfma_n64<<<gg, 256, 0, stream>>>(fpb, KFP, WfpT, KFP, Cp_fp, G, KFP / KS_FP);
    fp_finish<<<G, 64, 0, stream>>>(Cp_fp, KS_FP, G, bfp, zb);
  }

  // ---- CSR by dst + graph segment ptrs ----
  hipMemsetAsync(deg, 0, sizeof(int) * (2 * (size_t)NN + G), stream);
  count_deg<<<(E + 255) / 256, 256, 0, stream>>>(ei, E, deg);
  {
    int nb = (NN + 1023) / 1024;
    scan_p1<<<nb, 256, 0, stream>>>(deg, NN, bsum);
    scan_p2<<<1, 128, 0, stream>>>(bsum, bpre, nb, rowptr_n, NN);
    scan_p3<<<nb, 256, 0, stream>>>(deg, bpre, NN, rowptr_n);
  }
  fill_csr<<<(E + 255) / 256, 256, 0, stream>>>(ei, E, cursor, rowptr_n, csr_src);
  count_graph<<<(NN + 255) / 256, 256, 0, stream>>>(batch, NN, gcnt);
  {
    int nb = (G + 1023) / 1024;
    scan_p1<<<nb, 256, 0, stream>>>(gcnt, G, bsum);
    scan_p2<<<1, 128, 0, stream>>>(bsum, bpre, nb, rowptr_g, G);
    scan_p3<<<nb, 256, 0, stream>>>(gcnt, bpre, G, rowptr_g);
  }

  // ---- conv1 ----
  {
    dim3 gg(HC1 / 128, (NN + 127) / 128);
    gemm_mfma<1><<<gg, 256, 0, stream>>>(xb, W1T, h1b, NN, HC1, FIN);
  }
  compute_e_v<<<(NN + 7) / 8, 256, 0, stream>>>(h1b, a_src1, a_dst1, es1, ed1, NN, H, C1);
  alpha_kernel<<<(NN * H + 255) / 256, 256, 0, stream>>>(es1, ed1, rowptr_n, csr_src,
                                                         w1, wself1, NN, H);
  aggregate_b<<<(NN + 7) / 8, 256, 0, stream>>>(h1b, w1, wself1, rowptr_n, csr_src,
                                                b1, agg1b, NN, H, C1);

  // ---- conv2, by partition ----
  for (int p = 0; p < npart; ++p) {
    dim3 gg(Cpart / 128, (NN + 127) / 128);
    gemm_mfma<1><<<gg, 256, 0, stream>>>(agg1b, W2T + (size_t)p * Cpart * HC1, h2b,
                                         NN, Cpart, HC1);
    {
      int LPN = Cpart >> 3;
      int npb = 256 / LPN;
      compute_e_v<<<(NN + npb - 1) / npb, 256, 0, stream>>>(
          h2b, a_src2 + (size_t)p * Cpart, a_dst2 + (size_t)p * Cpart,
          es2, ed2, NN, HP, C2);
    }
    alpha_kernel<<<(NN * HP + 255) / 256, 256, 0, stream>>>(es2, ed2, rowptr_n, csr_src,
                                                            w2, wself2, NN, HP);
    {
      int CH8 = Cpart >> 3;
      int dpb = 256 / CH8;
      aggregate_b<<<(NN + dpb - 1) / dpb, 256, 0, stream>>>(
          h2b, w2, wself2, rowptr_n, csr_src, b2 + (size_t)p * Cpart, agg2b, NN, HP, C2);
    }
    pool_mean_zb<<<G, Cpart / 4, 0, stream>>>(agg2b, Cpart, rowptr_g, zb, p * Cpart);
  }

  // ---- head: zb @ Wfc1T (+bfc1, relu) @ Wfc2 (+bfc2) ----
  {
    dim3 gg(KS_Z, G / 128);
    gemm_mfma_n64<<<gg, 256, 0, stream>>>(zb, KZ, Wfc1T, KZ, Cp_z, G, KZ / KS_Z);
    mlp_finish<<<G, 64, 0, stream>>>(Cp_z, KS_Z, G, bfc1, Wfc2, bfc2, out);
  }
}